// Round 4
// baseline (625.878 us; speedup 1.0000x reference)
//
#include <hip/hip_runtime.h>

typedef unsigned short u16;
typedef __bf16 bf16x8 __attribute__((ext_vector_type(8)));
typedef unsigned short u16x8 __attribute__((ext_vector_type(8)));
typedef unsigned short u16x4 __attribute__((ext_vector_type(4)));
typedef float f32x4 __attribute__((ext_vector_type(4)));

__device__ __forceinline__ f32x4 mfma16(u16x8 a, u16x8 b, f32x4 c) {
    return __builtin_amdgcn_mfma_f32_16x16x32_bf16(
        __builtin_bit_cast(bf16x8, a), __builtin_bit_cast(bf16x8, b), c, 0, 0, 0);
}

// fp32 -> bf16 RNE
__device__ __forceinline__ u16 f2b(float f) {
    unsigned int u = __builtin_bit_cast(unsigned int, f);
    return (u16)((u + 0x7fffu + ((u >> 16) & 1u)) >> 16);
}

__device__ __forceinline__ f32x4 zero4() { f32x4 z = {0.f, 0.f, 0.f, 0.f}; return z; }

// ---------------------------------------------------------------- converts
__global__ __launch_bounds__(256) void cvt_bf16_kernel(const float* __restrict__ in,
                                                       u16* __restrict__ out, int n) {
    int i = (blockIdx.x * 256 + threadIdx.x) * 4;
    if (i >= n) return;
    float4 v = *reinterpret_cast<const float4*>(in + i);
    u16x4 o;
    o.x = f2b(v.x); o.y = f2b(v.y); o.z = f2b(v.z); o.w = f2b(v.w);
    *reinterpret_cast<u16x4*>(out + i) = o;
}

// ------------------------------------------------- mask storage detection
// flag=1 if mask stored as int32 (bytes at i%4!=0 all zero), else 0 (byte bools)
__global__ void detect_mask_kernel(const unsigned char* __restrict__ m, int* __restrict__ flag) {
    __shared__ int any;
    if (threadIdx.x == 0) any = 0;
    __syncthreads();
    int acc = 0;
    for (int i = threadIdx.x; i < 8192; i += 256)
        if (i & 3) acc |= m[i];
    if (acc) atomicOr(&any, 1);
    __syncthreads();
    if (threadIdx.x == 0) *flag = any ? 0 : 1;
}

// ---------------------------------------------------------------- GEMM C = A * B^T
// A: M x K bf16 row-major; Bt: N x K bf16 row-major. 128x128 tile, 4 waves (2x2),
// each wave 64x64 = 4x4 MFMA frags. BK=32. Reg-staged LDS with padded stride.
// EPI 0: scatter to Q(*0.125)/K/V in (B,H,T,D).  EPI 1: fp32 write to out.
template <int EPI>
__global__ __launch_bounds__(256)
void gemm_bt_kernel(const u16* __restrict__ A, const u16* __restrict__ Bt,
                    int M, int N, int K,
                    u16* __restrict__ qo, u16* __restrict__ ko, u16* __restrict__ vo,
                    float* __restrict__ fo) {
    constexpr int BK = 32, LDT = 40;  // 40 shorts = 80B row stride: 16B-aligned, 2-way banks
    __shared__ u16 Al[128 * LDT];
    __shared__ u16 Bl[128 * LDT];
    int tid = threadIdx.x;
    int wave = tid >> 6, lane = tid & 63;
    int l15 = lane & 15, l16 = lane >> 4;
    int wr = wave >> 1, wc = wave & 1;
    int bx = blockIdx.x, by = blockIdx.y;
    const u16* Ab = A + (size_t)by * 128 * K;
    const u16* Bb = Bt + (size_t)bx * 128 * K;
    int srow = tid >> 2, schunk = tid & 3;  // 64 rows x 4 chunks of 8 elems

    f32x4 acc[4][4];
#pragma unroll
    for (int m = 0; m < 4; m++)
#pragma unroll
        for (int n = 0; n < 4; n++) acc[m][n] = zero4();

    for (int k0 = 0; k0 < K; k0 += BK) {
        u16x8 av0 = *(const u16x8*)(Ab + (size_t)srow * K + k0 + schunk * 8);
        u16x8 av1 = *(const u16x8*)(Ab + (size_t)(srow + 64) * K + k0 + schunk * 8);
        u16x8 bv0 = *(const u16x8*)(Bb + (size_t)srow * K + k0 + schunk * 8);
        u16x8 bv1 = *(const u16x8*)(Bb + (size_t)(srow + 64) * K + k0 + schunk * 8);
        __syncthreads();
        *(u16x8*)&Al[srow * LDT + schunk * 8] = av0;
        *(u16x8*)&Al[(srow + 64) * LDT + schunk * 8] = av1;
        *(u16x8*)&Bl[srow * LDT + schunk * 8] = bv0;
        *(u16x8*)&Bl[(srow + 64) * LDT + schunk * 8] = bv1;
        __syncthreads();
        u16x8 af[4], bfr[4];
#pragma unroll
        for (int m = 0; m < 4; m++)
            af[m] = *(const u16x8*)&Al[(wr * 64 + m * 16 + l15) * LDT + l16 * 8];
#pragma unroll
        for (int n = 0; n < 4; n++)
            bfr[n] = *(const u16x8*)&Bl[(wc * 64 + n * 16 + l15) * LDT + l16 * 8];
#pragma unroll
        for (int m = 0; m < 4; m++)
#pragma unroll
            for (int n = 0; n < 4; n++) acc[m][n] = mfma16(af[m], bfr[n], acc[m][n]);
    }

#pragma unroll
    for (int m = 0; m < 4; m++) {
#pragma unroll
        for (int j = 0; j < 4; j++) {
            int row = by * 128 + wr * 64 + m * 16 + l16 * 4 + j;
#pragma unroll
            for (int n = 0; n < 4; n++) {
                int col = bx * 128 + wc * 64 + n * 16 + l15;
                float val = acc[m][n][j];
                if constexpr (EPI == 0) {
                    // row = t*4+b ; col = chunk*1024 + h*64 + d
                    int chunk = col >> 10, h = (col >> 6) & 15, d = col & 63;
                    int t = row >> 2, bI = row & 3;
                    if (chunk == 0) val *= 0.125f;  // fold softmax scale (exact pow2)
                    u16* dst = (chunk == 0) ? qo : (chunk == 1) ? ko : vo;
                    dst[((size_t)(bI * 16 + h) * 2048 + t) * 64 + d] = f2b(val);
                } else {
                    fo[(size_t)row * N + col] = val;
                }
            }
        }
    }
}

// ---------------------------------------------------------------- flash attention
// grid: (T/128, B*H). 4 waves/WG, 32 q-rows per wave. 32-key tiles.
__global__ __launch_bounds__(256)
void attn_kernel(const u16* __restrict__ Qg, const u16* __restrict__ Kg,
                 const u16* __restrict__ Vg, const void* __restrict__ maskp,
                 const int* __restrict__ flag, u16* __restrict__ ctx) {
    constexpr float LOG2E = 1.4426950408889634f;
    __shared__ u16 Kl[32 * 72];      // [key][d] stride 72 (144B: aligned, 2-way banks)
    __shared__ u16 Vt[64 * 40];      // [d][key] transposed, stride 40
    __shared__ u16 Pl[4][32 * 40];   // per-wave P relayout buffer

    int tid = threadIdx.x;
    int wave = tid >> 6, lane = tid & 63;
    int l15 = lane & 15, l16 = lane >> 4;
    int bh = blockIdx.y;
    int b = bh >> 4, h = bh & 15;
    size_t base = (size_t)bh * 2048 * 64;
    int q0 = blockIdx.x * 128 + wave * 32;

    int isInt = *flag;
    const unsigned char* m8 = (const unsigned char*)maskp;
    const int* m32 = (const int*)maskp;

    // Q fragments (already pre-scaled by 0.125 in GEMM1 epilogue)
    u16x8 aq[2][2];
#pragma unroll
    for (int qb = 0; qb < 2; qb++)
#pragma unroll
        for (int ks = 0; ks < 2; ks++)
            aq[qb][ks] = *(const u16x8*)(Qg + base + (size_t)(q0 + qb * 16 + l15) * 64 +
                                         ks * 32 + l16 * 8);

    f32x4 acc_o[2][4];
    float mrun[2][4], lsum[2][4];
#pragma unroll
    for (int qb = 0; qb < 2; qb++) {
#pragma unroll
        for (int db = 0; db < 4; db++) acc_o[qb][db] = zero4();
#pragma unroll
        for (int j = 0; j < 4; j++) { mrun[qb][j] = -1e30f; lsum[qb][j] = 0.f; }
    }

    int srow = tid >> 3, schunk = tid & 7;  // 32 rows x 8 chunks of 8 elems

    for (int s0 = 0; s0 < 2048; s0 += 32) {
        u16x8 kv = *(const u16x8*)(Kg + base + (size_t)(s0 + srow) * 64 + schunk * 8);
        u16x8 vv = *(const u16x8*)(Vg + base + (size_t)(s0 + srow) * 64 + schunk * 8);
        __syncthreads();
        *(u16x8*)&Kl[srow * 72 + schunk * 8] = kv;
#pragma unroll
        for (int i = 0; i < 8; i++) Vt[(schunk * 8 + i) * 40 + srow] = vv[i];
        __syncthreads();

        int ki = b * 2048 + s0 + l15;
        int pad0 = isInt ? (m32[ki] != 0) : (m8[ki] != 0);
        int pad1 = isInt ? (m32[ki + 16] != 0) : (m8[ki + 16] != 0);

        // S = Q * K^T   (2 q-blocks x 2 key-blocks, k over D=64)
        f32x4 sa[2][2];
        sa[0][0] = zero4(); sa[0][1] = zero4(); sa[1][0] = zero4(); sa[1][1] = zero4();
#pragma unroll
        for (int kb = 0; kb < 2; kb++)
#pragma unroll
            for (int ks = 0; ks < 2; ks++) {
                u16x8 bk = *(const u16x8*)&Kl[(kb * 16 + l15) * 72 + ks * 32 + l16 * 8];
                sa[0][kb] = mfma16(aq[0][ks], bk, sa[0][kb]);
                sa[1][kb] = mfma16(aq[1][ks], bk, sa[1][kb]);
            }

        // online softmax (acc layout: row=(lane>>4)*4+j, col=lane&15)
#pragma unroll
        for (int qb = 0; qb < 2; qb++) {
            float s0v[4], s1v[4], tm[4];
#pragma unroll
            for (int j = 0; j < 4; j++) {
                s0v[j] = pad0 ? -1e30f : sa[qb][0][j];
                s1v[j] = pad1 ? -1e30f : sa[qb][1][j];
                tm[j] = fmaxf(s0v[j], s1v[j]);
            }
#pragma unroll
            for (int j = 0; j < 4; j++) {
                tm[j] = fmaxf(tm[j], __shfl_xor(tm[j], 1));
                tm[j] = fmaxf(tm[j], __shfl_xor(tm[j], 2));
                tm[j] = fmaxf(tm[j], __shfl_xor(tm[j], 4));
                tm[j] = fmaxf(tm[j], __shfl_xor(tm[j], 8));
            }
#pragma unroll
            for (int j = 0; j < 4; j++) {
                float mnew = fmaxf(mrun[qb][j], tm[j]);
                float sc = exp2f((mrun[qb][j] - mnew) * LOG2E);
                mrun[qb][j] = mnew;
                float p0 = exp2f((s0v[j] - mnew) * LOG2E);
                float p1 = exp2f((s1v[j] - mnew) * LOG2E);
                lsum[qb][j] *= sc;
#pragma unroll
                for (int db = 0; db < 4; db++) acc_o[qb][db][j] *= sc;
                int prow = qb * 16 + l16 * 4 + j;
                Pl[wave][prow * 40 + l15] = f2b(p0);
                Pl[wave][prow * 40 + 16 + l15] = f2b(p1);
                float rs = p0 + p1;
                rs += __shfl_xor(rs, 1);
                rs += __shfl_xor(rs, 2);
                rs += __shfl_xor(rs, 4);
                rs += __shfl_xor(rs, 8);
                lsum[qb][j] += rs;
            }
        }
        __syncthreads();  // order Pl writes before Pl reads (same wave, be safe)

        // O += P * V   (A=P rows q, B^T = Vt[d][key])
#pragma unroll
        for (int qb = 0; qb < 2; qb++) {
            u16x8 ap = *(const u16x8*)&Pl[wave][(qb * 16 + l15) * 40 + l16 * 8];
#pragma unroll
            for (int db = 0; db < 4; db++) {
                u16x8 bv = *(const u16x8*)&Vt[(db * 16 + l15) * 40 + l16 * 8];
                acc_o[qb][db] = mfma16(ap, bv, acc_o[qb][db]);
            }
        }
    }

    // epilogue: ctx[(t*4+b)*1024 + h*64 + d]
#pragma unroll
    for (int qb = 0; qb < 2; qb++)
#pragma unroll
        for (int j = 0; j < 4; j++) {
            float inv = 1.0f / lsum[qb][j];
            int qg = q0 + qb * 16 + l16 * 4 + j;
            size_t mrow = (size_t)qg * 4 + b;
#pragma unroll
            for (int db = 0; db < 4; db++)
                ctx[mrow * 1024 + h * 64 + db * 16 + l15] = f2b(acc_o[qb][db][j] * inv);
        }
}

// ---------------------------------------------------------------- launch
extern "C" void kernel_launch(void* const* d_in, const int* in_sizes, int n_in,
                              void* d_out, int out_size, void* d_ws, size_t ws_size,
                              hipStream_t stream) {
    const float* x = (const float*)d_in[0];
    const float* wqkv = (const float*)d_in[1];
    const float* wo = (const float*)d_in[2];
    const void* mask = d_in[3];
    float* out = (float*)d_out;

    // workspace carve (all 16B aligned)
    char* ws = (char*)d_ws;
    int* flag = (int*)ws;                       // 16 B
    u16* xb = (u16*)(ws + 16);                  // 8388608 elems (reused as ctx later)
    u16* wqkvb = xb + 8388608;                  // 3145728
    u16* wob = wqkvb + 3145728;                 // 1048576
    u16* qw = wob + 1048576;                    // 8388608
    u16* kw = qw + 8388608;                     // 8388608
    u16* vw = kw + 8388608;                     // 8388608
    u16* ctx = xb;                              // reuse after GEMM1

    cvt_bf16_kernel<<<8192, 256, 0, stream>>>(x, xb, 8388608);
    cvt_bf16_kernel<<<3072, 256, 0, stream>>>(wqkv, wqkvb, 3145728);
    cvt_bf16_kernel<<<1024, 256, 0, stream>>>(wo, wob, 1048576);
    detect_mask_kernel<<<1, 256, 0, stream>>>((const unsigned char*)mask, flag);

    // QKV projection: M=8192, N=3072, K=1024
    gemm_bt_kernel<0><<<dim3(24, 64), 256, 0, stream>>>(xb, wqkvb, 8192, 3072, 1024,
                                                        qw, kw, vw, nullptr);
    // attention -> ctx (overwrites xb region; GEMM1 already consumed it)
    attn_kernel<<<dim3(16, 64), 256, 0, stream>>>(qw, kw, vw, mask, flag, ctx);
    // out projection: M=8192, N=1024, K=1024, fp32 out
    gemm_bt_kernel<1><<<dim3(8, 64), 256, 0, stream>>>(ctx, wob, 8192, 1024, 1024,
                                                       nullptr, nullptr, nullptr, out);
}

// Round 6
// 473.844 us; speedup vs baseline: 1.3209x; 1.3209x over previous
//
#include <hip/hip_runtime.h>

typedef unsigned short u16;
typedef __bf16 bf16x8 __attribute__((ext_vector_type(8)));
typedef unsigned short u16x8 __attribute__((ext_vector_type(8)));
typedef unsigned short u16x4 __attribute__((ext_vector_type(4)));
typedef float f32x4 __attribute__((ext_vector_type(4)));

__device__ __forceinline__ f32x4 mfma16(u16x8 a, u16x8 b, f32x4 c) {
    return __builtin_amdgcn_mfma_f32_16x16x32_bf16(
        __builtin_bit_cast(bf16x8, a), __builtin_bit_cast(bf16x8, b), c, 0, 0, 0);
}

// fp32 -> bf16 RNE
__device__ __forceinline__ u16 f2b(float f) {
    unsigned int u = __builtin_bit_cast(unsigned int, f);
    return (u16)((u + 0x7fffu + ((u >> 16) & 1u)) >> 16);
}

__device__ __forceinline__ f32x4 zero4() { f32x4 z = {0.f, 0.f, 0.f, 0.f}; return z; }

// async global->LDS direct copy, 16B per lane (m97 recipe)
typedef __attribute__((address_space(1))) const unsigned int gas_u32;
typedef __attribute__((address_space(3))) unsigned int las_u32;
__device__ __forceinline__ void gload16(const u16* g, u16* l) {
    __builtin_amdgcn_global_load_lds((gas_u32*)g, (las_u32*)l, 16, 0, 0);
}

// ---------------------------------------------------------------- converts
__global__ __launch_bounds__(256) void cvt_bf16_kernel(const float* __restrict__ in,
                                                       u16* __restrict__ out, int n) {
    int i = (blockIdx.x * 256 + threadIdx.x) * 4;
    if (i >= n) return;
    float4 v = *reinterpret_cast<const float4*>(in + i);
    u16x4 o;
    o.x = f2b(v.x); o.y = f2b(v.y); o.z = f2b(v.z); o.w = f2b(v.w);
    *reinterpret_cast<u16x4*>(out + i) = o;
}

// ------------------------------------------------- mask storage detection
__global__ void detect_mask_kernel(const unsigned char* __restrict__ m, int* __restrict__ flag) {
    __shared__ int any;
    if (threadIdx.x == 0) any = 0;
    __syncthreads();
    int acc = 0;
    for (int i = threadIdx.x; i < 8192; i += 256)
        if (i & 3) acc |= m[i];
    if (acc) atomicOr(&any, 1);
    __syncthreads();
    if (threadIdx.x == 0) *flag = any ? 0 : 1;
}

// ---------------------------------------------------------------- GEMM C = A * B^T
// A: M x K bf16 row-major; Bt: N x K bf16 row-major. 128x128 tile, 4 waves (2x2),
// 4x4 MFMA frags/wave. BK=32. global_load_lds width-16 staging, linear LDS.
// EPI 0: scatter to Q(*0.125*log2e)/K/V in (B,H,T,D).  EPI 1: fp32 write.
template <int EPI>
__global__ __launch_bounds__(256)
void gemm_bt_kernel(const u16* __restrict__ A, const u16* __restrict__ Bt,
                    int M, int N, int K,
                    u16* __restrict__ qo, u16* __restrict__ ko, u16* __restrict__ vo,
                    float* __restrict__ fo) {
    constexpr int BK = 32;
    __shared__ u16 Al[128 * BK];   // linear [row][32] (gload_lds: no padding allowed)
    __shared__ u16 Bl[128 * BK];
    int tid = threadIdx.x;
    int wave = tid >> 6, lane = tid & 63;
    int l15 = lane & 15, l16 = lane >> 4;
    int wr = wave >> 1, wc = wave & 1;
    int bx = blockIdx.x, by = blockIdx.y;

    // staging: 512 chunks of 16B per tile half; thread handles chunks tid, tid+256
    int c0 = tid, c1 = tid + 256;
    const u16* gA0 = A + (size_t)(by * 128 + (c0 >> 2)) * K + (c0 & 3) * 8;
    const u16* gA1 = A + (size_t)(by * 128 + (c1 >> 2)) * K + (c1 & 3) * 8;
    const u16* gB0 = Bt + (size_t)(bx * 128 + (c0 >> 2)) * K + (c0 & 3) * 8;
    const u16* gB1 = Bt + (size_t)(bx * 128 + (c1 >> 2)) * K + (c1 & 3) * 8;
    u16* lA0 = Al + c0 * 8; u16* lA1 = Al + c1 * 8;
    u16* lB0 = Bl + c0 * 8; u16* lB1 = Bl + c1 * 8;

    f32x4 acc[4][4];
#pragma unroll
    for (int m = 0; m < 4; m++)
#pragma unroll
        for (int n = 0; n < 4; n++) acc[m][n] = zero4();

    for (int k0 = 0; k0 < K; k0 += BK) {
        __syncthreads();                 // prior ds_reads drained before overwrite
        gload16(gA0 + k0, lA0);
        gload16(gA1 + k0, lA1);
        gload16(gB0 + k0, lB0);
        gload16(gB1 + k0, lB1);
        __syncthreads();                 // vmcnt(0) drain -> tile visible
        u16x8 af[4], bfr[4];
#pragma unroll
        for (int m = 0; m < 4; m++)
            af[m] = *(const u16x8*)&Al[(wr * 64 + m * 16 + l15) * BK + l16 * 8];
#pragma unroll
        for (int n = 0; n < 4; n++)
            bfr[n] = *(const u16x8*)&Bl[(wc * 64 + n * 16 + l15) * BK + l16 * 8];
#pragma unroll
        for (int m = 0; m < 4; m++)
#pragma unroll
            for (int n = 0; n < 4; n++) acc[m][n] = mfma16(af[m], bfr[n], acc[m][n]);
    }

#pragma unroll
    for (int m = 0; m < 4; m++) {
#pragma unroll
        for (int j = 0; j < 4; j++) {
            int row = by * 128 + wr * 64 + m * 16 + l16 * 4 + j;
#pragma unroll
            for (int n = 0; n < 4; n++) {
                int col = bx * 128 + wc * 64 + n * 16 + l15;
                float val = acc[m][n][j];
                if constexpr (EPI == 0) {
                    int chunk = col >> 10, h = (col >> 6) & 15, d = col & 63;
                    int t = row >> 2, bI = row & 3;
                    // fold softmax scale AND log2(e) into Q (exp2 domain downstream)
                    if (chunk == 0) val *= 0.18033688011112042f;
                    u16* dst = (chunk == 0) ? qo : (chunk == 1) ? ko : vo;
                    dst[((size_t)(bI * 16 + h) * 2048 + t) * 64 + d] = f2b(val);
                } else {
                    fo[(size_t)row * N + col] = val;
                }
            }
        }
    }
}

// ---------------------------------------------------------------- flash attention
// grid: (T/128, B*H). 4 waves/WG, 32 q-rows per wave. 32-key tiles.
// Scores are in exp2 domain (Q pre-scaled by 0.125*log2e).
__global__ __launch_bounds__(256)
void attn_kernel(const u16* __restrict__ Qg, const u16* __restrict__ Kg,
                 const u16* __restrict__ Vg, const void* __restrict__ maskp,
                 const int* __restrict__ flag, u16* __restrict__ ctx) {
    __shared__ u16 Kl[32 * 72];      // [key][d] stride 72
    __shared__ u16 Vt[64 * 40];      // [d][key] transposed, stride 40
    __shared__ u16 Pl[4][32 * 40];   // per-wave P relayout buffer

    int tid = threadIdx.x;
    int wave = tid >> 6, lane = tid & 63;
    int l15 = lane & 15, l16 = lane >> 4;
    int bh = blockIdx.y;
    int b = bh >> 4, h = bh & 15;
    size_t base = (size_t)bh * 2048 * 64;
    int q0 = blockIdx.x * 128 + wave * 32;

    int isInt = *flag;
    const unsigned char* m8 = (const unsigned char*)maskp;
    const int* m32 = (const int*)maskp;

    u16x8 aq[2][2];
#pragma unroll
    for (int qb = 0; qb < 2; qb++)
#pragma unroll
        for (int ks = 0; ks < 2; ks++)
            aq[qb][ks] = *(const u16x8*)(Qg + base + (size_t)(q0 + qb * 16 + l15) * 64 +
                                         ks * 32 + l16 * 8);

    f32x4 acc_o[2][4];
    float mrun[2][4], plsum[2][4];   // plsum: per-LANE partial row sum (reduced at end)
#pragma unroll
    for (int qb = 0; qb < 2; qb++) {
#pragma unroll
        for (int db = 0; db < 4; db++) acc_o[qb][db] = zero4();
#pragma unroll
        for (int j = 0; j < 4; j++) { mrun[qb][j] = -1e30f; plsum[qb][j] = 0.f; }
    }

    int srow = tid >> 3, schunk = tid & 7;  // 32 rows x 8 chunks of 8 elems

    for (int s0 = 0; s0 < 2048; s0 += 32) {
        u16x8 kv = *(const u16x8*)(Kg + base + (size_t)(s0 + srow) * 64 + schunk * 8);
        u16x8 vv = *(const u16x8*)(Vg + base + (size_t)(s0 + srow) * 64 + schunk * 8);
        __syncthreads();
        *(u16x8*)&Kl[srow * 72 + schunk * 8] = kv;
        // rotated store order: per-instruction banks 2-way instead of ~8-way
#pragma unroll
        for (int s = 0; s < 8; s++) {
            int i = (srow + schunk + s) & 7;
            Vt[(schunk * 8 + i) * 40 + srow] = vv[i];
        }
        __syncthreads();

        int ki = b * 2048 + s0 + l15;
        int pad0 = isInt ? (m32[ki] != 0) : (m8[ki] != 0);
        int pad1 = isInt ? (m32[ki + 16] != 0) : (m8[ki + 16] != 0);

        // S = Q * K^T (exp2 domain)
        f32x4 sa[2][2];
        sa[0][0] = zero4(); sa[0][1] = zero4(); sa[1][0] = zero4(); sa[1][1] = zero4();
#pragma unroll
        for (int kb = 0; kb < 2; kb++)
#pragma unroll
            for (int ks = 0; ks < 2; ks++) {
                u16x8 bk = *(const u16x8*)&Kl[(kb * 16 + l15) * 72 + ks * 32 + l16 * 8];
                sa[0][kb] = mfma16(aq[0][ks], bk, sa[0][kb]);
                sa[1][kb] = mfma16(aq[1][ks], bk, sa[1][kb]);
            }

        // lazy-max online softmax: rescale only when the wave votes growth > 4
#pragma unroll
        for (int qb = 0; qb < 2; qb++) {
            float s0v[4], s1v[4];
            float gl = -1e30f;
#pragma unroll
            for (int j = 0; j < 4; j++) {
                s0v[j] = pad0 ? -1e30f : sa[qb][0][j];
                s1v[j] = pad1 ? -1e30f : sa[qb][1][j];
                gl = fmaxf(gl, fmaxf(s0v[j], s1v[j]) - mrun[qb][j]);
            }
            if (__any(gl > 4.0f)) {
                float tm[4];
#pragma unroll
                for (int j = 0; j < 4; j++) tm[j] = fmaxf(s0v[j], s1v[j]);
#pragma unroll
                for (int j = 0; j < 4; j++) {
                    tm[j] = fmaxf(tm[j], __shfl_xor(tm[j], 1));
                    tm[j] = fmaxf(tm[j], __shfl_xor(tm[j], 2));
                    tm[j] = fmaxf(tm[j], __shfl_xor(tm[j], 4));
                    tm[j] = fmaxf(tm[j], __shfl_xor(tm[j], 8));
                }
#pragma unroll
                for (int j = 0; j < 4; j++) {
                    float mnew = fmaxf(mrun[qb][j], tm[j]);
                    float sc = exp2f(mrun[qb][j] - mnew);
                    mrun[qb][j] = mnew;
                    plsum[qb][j] *= sc;
#pragma unroll
                    for (int db = 0; db < 4; db++) acc_o[qb][db][j] *= sc;
                }
            }
#pragma unroll
            for (int j = 0; j < 4; j++) {
                float p0 = exp2f(s0v[j] - mrun[qb][j]);   // bounded by 2^4
                float p1 = exp2f(s1v[j] - mrun[qb][j]);
                int prow = qb * 16 + l16 * 4 + j;
                Pl[wave][prow * 40 + l15] = f2b(p0);
                Pl[wave][prow * 40 + 16 + l15] = f2b(p1);
                plsum[qb][j] += p0 + p1;
            }
        }

        // O += P * V
#pragma unroll
        for (int qb = 0; qb < 2; qb++) {
            u16x8 ap = *(const u16x8*)&Pl[wave][(qb * 16 + l15) * 40 + l16 * 8];
#pragma unroll
            for (int db = 0; db < 4; db++) {
                u16x8 bv = *(const u16x8*)&Vt[(db * 16 + l15) * 40 + l16 * 8];
                acc_o[qb][db] = mfma16(ap, bv, acc_o[qb][db]);
            }
        }
    }

    // epilogue: reduce row sums once, then ctx[(t*4+b)*1024 + h*64 + d]
#pragma unroll
    for (int qb = 0; qb < 2; qb++)
#pragma unroll
        for (int j = 0; j < 4; j++) {
            float rs = plsum[qb][j];
            rs += __shfl_xor(rs, 1);
            rs += __shfl_xor(rs, 2);
            rs += __shfl_xor(rs, 4);
            rs += __shfl_xor(rs, 8);
            float inv = 1.0f / rs;
            int qg = q0 + qb * 16 + l16 * 4 + j;
            size_t mrow = (size_t)qg * 4 + b;
#pragma unroll
            for (int db = 0; db < 4; db++)
                ctx[mrow * 1024 + h * 64 + db * 16 + l15] = f2b(acc_o[qb][db][j] * inv);
        }
}

// ---------------------------------------------------------------- launch
extern "C" void kernel_launch(void* const* d_in, const int* in_sizes, int n_in,
                              void* d_out, int out_size, void* d_ws, size_t ws_size,
                              hipStream_t stream) {
    const float* x = (const float*)d_in[0];
    const float* wqkv = (const float*)d_in[1];
    const float* wo = (const float*)d_in[2];
    const void* mask = d_in[3];
    float* out = (float*)d_out;

    char* ws = (char*)d_ws;
    int* flag = (int*)ws;                       // 16 B
    u16* xb = (u16*)(ws + 16);                  // 8388608 elems (reused as ctx later)
    u16* wqkvb = xb + 8388608;                  // 3145728
    u16* wob = wqkvb + 3145728;                 // 1048576
    u16* qw = wob + 1048576;                    // 8388608
    u16* kw = qw + 8388608;                     // 8388608
    u16* vw = kw + 8388608;                     // 8388608
    u16* ctx = xb;                              // reuse after GEMM1

    cvt_bf16_kernel<<<8192, 256, 0, stream>>>(x, xb, 8388608);
    cvt_bf16_kernel<<<3072, 256, 0, stream>>>(wqkv, wqkvb, 3145728);
    cvt_bf16_kernel<<<1024, 256, 0, stream>>>(wo, wob, 1048576);
    detect_mask_kernel<<<1, 256, 0, stream>>>((const unsigned char*)mask, flag);

    gemm_bt_kernel<0><<<dim3(24, 64), 256, 0, stream>>>(xb, wqkvb, 8192, 3072, 1024,
                                                        qw, kw, vw, nullptr);
    attn_kernel<<<dim3(16, 64), 256, 0, stream>>>(qw, kw, vw, mask, flag, ctx);
    gemm_bt_kernel<1><<<dim3(8, 64), 256, 0, stream>>>(ctx, wob, 8192, 1024, 1024,
                                                       nullptr, nullptr, nullptr, out);
}

// Round 8
// 451.875 us; speedup vs baseline: 1.3851x; 1.0486x over previous
//
#include <hip/hip_runtime.h>

typedef unsigned short u16;
typedef __bf16 bf16x8 __attribute__((ext_vector_type(8)));
typedef unsigned short u16x8 __attribute__((ext_vector_type(8)));
typedef unsigned short u16x4 __attribute__((ext_vector_type(4)));
typedef float f32x4 __attribute__((ext_vector_type(4)));

__device__ __forceinline__ f32x4 mfma16(u16x8 a, u16x8 b, f32x4 c) {
    return __builtin_amdgcn_mfma_f32_16x16x32_bf16(
        __builtin_bit_cast(bf16x8, a), __builtin_bit_cast(bf16x8, b), c, 0, 0, 0);
}

// fp32 -> bf16 RNE
__device__ __forceinline__ u16 f2b(float f) {
    unsigned int u = __builtin_bit_cast(unsigned int, f);
    return (u16)((u + 0x7fffu + ((u >> 16) & 1u)) >> 16);
}

__device__ __forceinline__ f32x4 zero4() { f32x4 z = {0.f, 0.f, 0.f, 0.f}; return z; }

// async global->LDS direct copy, 16B per lane (m97 recipe)
typedef __attribute__((address_space(1))) const unsigned int gas_u32;
typedef __attribute__((address_space(3))) unsigned int las_u32;
__device__ __forceinline__ void gload16(const u16* g, u16* l) {
    __builtin_amdgcn_global_load_lds((gas_u32*)g, (las_u32*)l, 16, 0, 0);
}

// LDS HW-transpose read (Model B semantics): the per-lane address selects a
// 128B-aligned window (addr & ~127) and an 8B slot s=(addr&127)>>3; lane
// receives column s of the window viewed as a 4x16 row-major bf16 matrix:
// elem j = window_byte + 2*s + 32*j.
__device__ __forceinline__ u16x4 tr16(unsigned off) {
    u16x4 r;
    asm volatile("ds_read_b64_tr_b16 %0, %1" : "=v"(r) : "v"(off));
    return r;
}

// ---------------------------------------------------------------- converts
__global__ __launch_bounds__(256) void cvt_bf16_kernel(const float* __restrict__ in,
                                                       u16* __restrict__ out, int n) {
    int i = (blockIdx.x * 256 + threadIdx.x) * 4;
    if (i >= n) return;
    float4 v = *reinterpret_cast<const float4*>(in + i);
    u16x4 o;
    o.x = f2b(v.x); o.y = f2b(v.y); o.z = f2b(v.z); o.w = f2b(v.w);
    *reinterpret_cast<u16x4*>(out + i) = o;
}

// ------------------------------------------------- mask storage detection
__global__ void detect_mask_kernel(const unsigned char* __restrict__ m, int* __restrict__ flag) {
    __shared__ int any;
    if (threadIdx.x == 0) any = 0;
    __syncthreads();
    int acc = 0;
    for (int i = threadIdx.x; i < 8192; i += 256)
        if (i & 3) acc |= m[i];
    if (acc) atomicOr(&any, 1);
    __syncthreads();
    if (threadIdx.x == 0) *flag = any ? 0 : 1;
}

// ---------------------------------------------------------------- GEMM C = A * B^T
// m97-exact: 128x128 tile, BK=64, 4 waves (2x2), 4x4 frags, global_load_lds w16,
// 2 barriers per 64-K step. EPI 0: scatter Q(*0.125*log2e)/K/V. EPI 1: fp32 out.
template <int EPI>
__global__ __launch_bounds__(256)
void gemm_bt_kernel(const u16* __restrict__ A, const u16* __restrict__ Bt,
                    int M, int N, int K,
                    u16* __restrict__ qo, u16* __restrict__ ko, u16* __restrict__ vo,
                    float* __restrict__ fo) {
    constexpr int BK = 64;
    __shared__ __align__(16) u16 Al[128 * BK];   // 16KB, linear (gload_lds contract)
    __shared__ __align__(16) u16 Bl[128 * BK];
    int tid = threadIdx.x;
    int wave = tid >> 6, lane = tid & 63;
    int l15 = lane & 15, l16 = lane >> 4;
    int wr = wave >> 1, wc = wave & 1;
    int bx = blockIdx.x, by = blockIdx.y;

    // 1024 16B-chunks per tile: thread q-th chunk c=tid+q*256; row=c>>3, kc=c&7
    const u16* gA[4]; const u16* gB[4]; u16* lA[4]; u16* lB[4];
#pragma unroll
    for (int q = 0; q < 4; q++) {
        int c = tid + q * 256;
        gA[q] = A + (size_t)(by * 128 + (c >> 3)) * K + (c & 7) * 8;
        gB[q] = Bt + (size_t)(bx * 128 + (c >> 3)) * K + (c & 7) * 8;
        lA[q] = Al + c * 8;
        lB[q] = Bl + c * 8;
    }

    f32x4 acc[4][4];
#pragma unroll
    for (int m = 0; m < 4; m++)
#pragma unroll
        for (int n = 0; n < 4; n++) acc[m][n] = zero4();

    for (int k0 = 0; k0 < K; k0 += BK) {
        __syncthreads();                 // prior ds_reads drained before overwrite
#pragma unroll
        for (int q = 0; q < 4; q++) {
            gload16(gA[q] + k0, lA[q]);
            gload16(gB[q] + k0, lB[q]);
        }
        __syncthreads();                 // vmcnt(0) drain -> tile visible
#pragma unroll
        for (int ks = 0; ks < 2; ks++) {
            u16x8 af[4], bfr[4];
#pragma unroll
            for (int m = 0; m < 4; m++)
                af[m] = *(const u16x8*)&Al[(wr * 64 + m * 16 + l15) * BK + ks * 32 + l16 * 8];
#pragma unroll
            for (int n = 0; n < 4; n++)
                bfr[n] = *(const u16x8*)&Bl[(wc * 64 + n * 16 + l15) * BK + ks * 32 + l16 * 8];
#pragma unroll
            for (int m = 0; m < 4; m++)
#pragma unroll
                for (int n = 0; n < 4; n++) acc[m][n] = mfma16(af[m], bfr[n], acc[m][n]);
        }
    }

#pragma unroll
    for (int m = 0; m < 4; m++) {
#pragma unroll
        for (int j = 0; j < 4; j++) {
            int row = by * 128 + wr * 64 + m * 16 + l16 * 4 + j;
#pragma unroll
            for (int n = 0; n < 4; n++) {
                int col = bx * 128 + wc * 64 + n * 16 + l15;
                float val = acc[m][n][j];
                if constexpr (EPI == 0) {
                    int chunk = col >> 10, h = (col >> 6) & 15, d = col & 63;
                    int t = row >> 2, bI = row & 3;
                    // fold softmax scale AND log2(e) into Q (exp2 domain downstream)
                    if (chunk == 0) val *= 0.18033688011112042f;
                    u16* dst = (chunk == 0) ? qo : (chunk == 1) ? ko : vo;
                    dst[((size_t)(bI * 16 + h) * 2048 + t) * 64 + d] = f2b(val);
                } else {
                    fo[(size_t)row * N + col] = val;
                }
            }
        }
    }
}

// ---------------------------------------------------------------- flash attention
// grid: (T/128, B*H). 4 waves/WG, 32 q-rows/wave, 32-key tiles.
// Scores in exp2 domain. V staged subtiled [db=4][key=32][dlo=16]; PV B-frags
// via ds_read_b64_tr_b16 (Model B addressing: window + 8B slot per column).
__global__ __launch_bounds__(256)
void attn_kernel(const u16* __restrict__ Qg, const u16* __restrict__ Kg,
                 const u16* __restrict__ Vg, const void* __restrict__ maskp,
                 const int* __restrict__ flag, u16* __restrict__ ctx) {
    __shared__ __align__(16) u16 Kl[32 * 72];     // [key][d] stride 72
    __shared__ __align__(128) u16 Vs[2048];       // [db=4][key=32][dlo=16], 128B windows
    __shared__ __align__(16) u16 Pl[4][32 * 40];  // per-wave P relayout

    int tid = threadIdx.x;
    int wave = tid >> 6, lane = tid & 63;
    int l15 = lane & 15, l16 = lane >> 4;
    int bh = blockIdx.y;
    int b = bh >> 4, h = bh & 15;
    size_t base = (size_t)bh * 2048 * 64;
    int q0 = blockIdx.x * 128 + wave * 32;

    int isInt = *flag;
    const unsigned char* m8 = (const unsigned char*)maskp;
    const int* m32 = (const int*)maskp;

    u16x8 aq[2][2];
#pragma unroll
    for (int qb = 0; qb < 2; qb++)
#pragma unroll
        for (int ks = 0; ks < 2; ks++)
            aq[qb][ks] = *(const u16x8*)(Qg + base + (size_t)(q0 + qb * 16 + l15) * 64 +
                                         ks * 32 + l16 * 8);

    f32x4 acc_o[2][4];
    float mrun[2][4], plsum[2][4];
#pragma unroll
    for (int qb = 0; qb < 2; qb++) {
#pragma unroll
        for (int db = 0; db < 4; db++) acc_o[qb][db] = zero4();
#pragma unroll
        for (int j = 0; j < 4; j++) { mrun[qb][j] = -1e30f; plsum[qb][j] = 0.f; }
    }

    int srow = tid >> 3, schunk = tid & 7;  // key row 0..31, d-chunk 0..7
    const u16* kg = Kg + base + (size_t)srow * 64 + schunk * 8;
    const u16* vg = Vg + base + (size_t)srow * 64 + schunk * 8;
    u16* kldst = &Kl[srow * 72 + schunk * 8];
    // Vs[db][key][dlo]: db=schunk>>1, dlo base=(schunk&1)*8 -> one static u16x8 store
    u16* vsdst = &Vs[(schunk >> 1) * 512 + srow * 16 + (schunk & 1) * 8];
    // tr-read (Model B): window(db,l16) at byte db*1024 + l16*256; column l15 -> slot
    // byte +8*l15; elem j = key l16*8+j, d=db*16+l15; t1 at +128B = keys +4.
    unsigned vtrb = (unsigned)(uintptr_t)(&Vs[0]) + (unsigned)(l16 * 256 + l15 * 8);

    u16x8 kv = *(const u16x8*)kg;     // tile 0
    u16x8 vv = *(const u16x8*)vg;

    for (int it = 0; it < 64; ++it) {
        int s0 = it * 32;
        __syncthreads();              // prior tile's LDS reads done
        *(u16x8*)kldst = kv;
        *(u16x8*)vsdst = vv;
        int snext = (s0 + 32) & 2047; // wraps to 0 on last iter (harmless)
        u16x8 kv2 = *(const u16x8*)(kg + (size_t)snext * 64);   // T14: in flight
        u16x8 vv2 = *(const u16x8*)(vg + (size_t)snext * 64);   // during compute
        __syncthreads();              // staged tile visible

        int ki = b * 2048 + s0 + l15;
        int pad0 = isInt ? (m32[ki] != 0) : (m8[ki] != 0);
        int pad1 = isInt ? (m32[ki + 16] != 0) : (m8[ki + 16] != 0);

        // S = Q * K^T (exp2 domain)
        f32x4 sa[2][2];
        sa[0][0] = zero4(); sa[0][1] = zero4(); sa[1][0] = zero4(); sa[1][1] = zero4();
#pragma unroll
        for (int kb = 0; kb < 2; kb++)
#pragma unroll
            for (int ks = 0; ks < 2; ks++) {
                u16x8 bk = *(const u16x8*)&Kl[(kb * 16 + l15) * 72 + ks * 32 + l16 * 8];
                sa[0][kb] = mfma16(aq[0][ks], bk, sa[0][kb]);
                sa[1][kb] = mfma16(aq[1][ks], bk, sa[1][kb]);
            }

        // lazy-max online softmax (T13, thr=8: P bounded by 2^8)
#pragma unroll
        for (int qb = 0; qb < 2; qb++) {
            float s0v[4], s1v[4];
            float gl = -1e30f;
#pragma unroll
            for (int j = 0; j < 4; j++) {
                s0v[j] = pad0 ? -1e30f : sa[qb][0][j];
                s1v[j] = pad1 ? -1e30f : sa[qb][1][j];
                gl = fmaxf(gl, fmaxf(s0v[j], s1v[j]) - mrun[qb][j]);
            }
            if (__any(gl > 8.0f)) {
                float tm[4];
#pragma unroll
                for (int j = 0; j < 4; j++) tm[j] = fmaxf(s0v[j], s1v[j]);
#pragma unroll
                for (int j = 0; j < 4; j++) {
                    tm[j] = fmaxf(tm[j], __shfl_xor(tm[j], 1));
                    tm[j] = fmaxf(tm[j], __shfl_xor(tm[j], 2));
                    tm[j] = fmaxf(tm[j], __shfl_xor(tm[j], 4));
                    tm[j] = fmaxf(tm[j], __shfl_xor(tm[j], 8));
                }
#pragma unroll
                for (int j = 0; j < 4; j++) {
                    float mnew = fmaxf(mrun[qb][j], tm[j]);
                    float sc = exp2f(mrun[qb][j] - mnew);
                    mrun[qb][j] = mnew;
                    plsum[qb][j] *= sc;
#pragma unroll
                    for (int db = 0; db < 4; db++) acc_o[qb][db][j] *= sc;
                }
            }
#pragma unroll
            for (int j = 0; j < 4; j++) {
                float p0 = exp2f(s0v[j] - mrun[qb][j]);
                float p1 = exp2f(s1v[j] - mrun[qb][j]);
                int prow = qb * 16 + l16 * 4 + j;
                Pl[wave][prow * 40 + l15] = f2b(p0);
                Pl[wave][prow * 40 + 16 + l15] = f2b(p1);
                plsum[qb][j] += p0 + p1;
            }
        }

        // O += P * V   (A = Pl rows, B-frag via HW transpose reads of Vs)
        u16x8 ap0 = *(const u16x8*)&Pl[wave][(0 * 16 + l15) * 40 + l16 * 8];
        u16x8 ap1 = *(const u16x8*)&Pl[wave][(1 * 16 + l15) * 40 + l16 * 8];
#pragma unroll
        for (int db = 0; db < 4; db++) {
            u16x4 t0 = tr16(vtrb + db * 1024);         // keys l16*8+0..3, d=db*16+l15
            u16x4 t1 = tr16(vtrb + db * 1024 + 128);   // keys l16*8+4..7
            asm volatile("s_waitcnt lgkmcnt(0)" ::: "memory");
            __builtin_amdgcn_sched_barrier(0);         // rule #18: pin MFMA after wait
            u16x8 bv = {t0[0], t0[1], t0[2], t0[3], t1[0], t1[1], t1[2], t1[3]};
            acc_o[0][db] = mfma16(ap0, bv, acc_o[0][db]);
            acc_o[1][db] = mfma16(ap1, bv, acc_o[1][db]);
        }
        kv = kv2; vv = vv2;
    }

    // epilogue: reduce row sums once, then ctx[(t*4+b)*1024 + h*64 + d]
#pragma unroll
    for (int qb = 0; qb < 2; qb++)
#pragma unroll
        for (int j = 0; j < 4; j++) {
            float rs = plsum[qb][j];
            rs += __shfl_xor(rs, 1);
            rs += __shfl_xor(rs, 2);
            rs += __shfl_xor(rs, 4);
            rs += __shfl_xor(rs, 8);
            float inv = 1.0f / rs;
            int qg = q0 + qb * 16 + l16 * 4 + j;
            size_t mrow = (size_t)qg * 4 + b;
#pragma unroll
            for (int db = 0; db < 4; db++)
                ctx[mrow * 1024 + h * 64 + db * 16 + l15] = f2b(acc_o[qb][db][j] * inv);
        }
}

// ---------------------------------------------------------------- launch
extern "C" void kernel_launch(void* const* d_in, const int* in_sizes, int n_in,
                              void* d_out, int out_size, void* d_ws, size_t ws_size,
                              hipStream_t stream) {
    const float* x = (const float*)d_in[0];
    const float* wqkv = (const float*)d_in[1];
    const float* wo = (const float*)d_in[2];
    const void* mask = d_in[3];
    float* out = (float*)d_out;

    char* ws = (char*)d_ws;
    int* flag = (int*)ws;                       // 16 B
    u16* xb = (u16*)(ws + 16);                  // 8388608 elems (reused as ctx later)
    u16* wqkvb = xb + 8388608;                  // 3145728
    u16* wob = wqkvb + 3145728;                 // 1048576
    u16* qw = wob + 1048576;                    // 8388608
    u16* kw = qw + 8388608;                     // 8388608
    u16* vw = kw + 8388608;                     // 8388608
    u16* ctx = xb;                              // reuse after GEMM1

    cvt_bf16_kernel<<<8192, 256, 0, stream>>>(x, xb, 8388608);
    cvt_bf16_kernel<<<3072, 256, 0, stream>>>(wqkv, wqkvb, 3145728);
    cvt_bf16_kernel<<<1024, 256, 0, stream>>>(wo, wob, 1048576);
    detect_mask_kernel<<<1, 256, 0, stream>>>((const unsigned char*)mask, flag);

    gemm_bt_kernel<0><<<dim3(24, 64), 256, 0, stream>>>(xb, wqkvb, 8192, 3072, 1024,
                                                        qw, kw, vw, nullptr);
    attn_kernel<<<dim3(16, 64), 256, 0, stream>>>(qw, kw, vw, mask, flag, ctx);
    gemm_bt_kernel<1><<<dim3(8, 64), 256, 0, stream>>>(ctx, wob, 8192, 1024, 1024,
                                                       nullptr, nullptr, nullptr, out);
}

// Round 10
// 414.257 us; speedup vs baseline: 1.5108x; 1.0908x over previous
//
#include <hip/hip_runtime.h>

typedef unsigned short u16;
typedef __bf16 bf16x8 __attribute__((ext_vector_type(8)));
typedef unsigned short u16x8 __attribute__((ext_vector_type(8)));
typedef unsigned short u16x4 __attribute__((ext_vector_type(4)));
typedef float f32x4 __attribute__((ext_vector_type(4)));

__device__ __forceinline__ f32x4 mfma16(u16x8 a, u16x8 b, f32x4 c) {
    return __builtin_amdgcn_mfma_f32_16x16x32_bf16(
        __builtin_bit_cast(bf16x8, a), __builtin_bit_cast(bf16x8, b), c, 0, 0, 0);
}

// fp32 -> bf16 RNE
__device__ __forceinline__ u16 f2b(float f) {
    unsigned int u = __builtin_bit_cast(unsigned int, f);
    return (u16)((u + 0x7fffu + ((u >> 16) & 1u)) >> 16);
}

__device__ __forceinline__ f32x4 zero4() { f32x4 z = {0.f, 0.f, 0.f, 0.f}; return z; }

// async global->LDS direct copy, 16B per lane (m97 recipe)
typedef __attribute__((address_space(1))) const unsigned int gas_u32;
typedef __attribute__((address_space(3))) unsigned int las_u32;
__device__ __forceinline__ void gload16(const u16* g, u16* l) {
    __builtin_amdgcn_global_load_lds((gas_u32*)g, (las_u32*)l, 16, 0, 0);
}

// LDS HW-transpose read (Model B, validated round 8): addr selects a 128B
// window (addr & ~127) and 8B slot s=(addr&127)>>3; lane gets column s of the
// window viewed as 4x16 row-major bf16: elem j = window + 2*s + 32*j.
__device__ __forceinline__ u16x4 tr16(unsigned off) {
    u16x4 r;
    asm volatile("ds_read_b64_tr_b16 %0, %1" : "=v"(r) : "v"(off));
    return r;
}

// ---------------------------------------------------------------- converts
__global__ __launch_bounds__(256) void cvt_bf16_kernel(const float* __restrict__ in,
                                                       u16* __restrict__ out, int n) {
    int i = (blockIdx.x * 256 + threadIdx.x) * 4;
    if (i >= n) return;
    float4 v = *reinterpret_cast<const float4*>(in + i);
    u16x4 o;
    o.x = f2b(v.x); o.y = f2b(v.y); o.z = f2b(v.z); o.w = f2b(v.w);
    *reinterpret_cast<u16x4*>(out + i) = o;
}

// ------------------------------------------------- mask storage detection
__global__ void detect_mask_kernel(const unsigned char* __restrict__ m, int* __restrict__ flag) {
    __shared__ int any;
    if (threadIdx.x == 0) any = 0;
    __syncthreads();
    int acc = 0;
    for (int i = threadIdx.x; i < 8192; i += 256)
        if (i & 3) acc |= m[i];
    if (acc) atomicOr(&any, 1);
    __syncthreads();
    if (threadIdx.x == 0) *flag = any ? 0 : 1;
}

// ---------------------------------------------------------------- GEMM C = A * B^T
// m97-exact: 128x128 tile, BK=64, 4 waves (2x2), 4x4 frags, global_load_lds w16,
// 2 barriers per 64-K step. EPI 0: scatter Q(*0.125*log2e)/K/V. EPI 1: fp32 out.
template <int EPI>
__global__ __launch_bounds__(256)
void gemm_bt_kernel(const u16* __restrict__ A, const u16* __restrict__ Bt,
                    int M, int N, int K,
                    u16* __restrict__ qo, u16* __restrict__ ko, u16* __restrict__ vo,
                    float* __restrict__ fo) {
    constexpr int BK = 64;
    __shared__ __align__(16) u16 Al[128 * BK];   // 16KB, linear (gload_lds contract)
    __shared__ __align__(16) u16 Bl[128 * BK];
    int tid = threadIdx.x;
    int wave = tid >> 6, lane = tid & 63;
    int l15 = lane & 15, l16 = lane >> 4;
    int wr = wave >> 1, wc = wave & 1;
    int bx = blockIdx.x, by = blockIdx.y;

    const u16* gA[4]; const u16* gB[4]; u16* lA[4]; u16* lB[4];
#pragma unroll
    for (int q = 0; q < 4; q++) {
        int c = tid + q * 256;
        gA[q] = A + (size_t)(by * 128 + (c >> 3)) * K + (c & 7) * 8;
        gB[q] = Bt + (size_t)(bx * 128 + (c >> 3)) * K + (c & 7) * 8;
        lA[q] = Al + c * 8;
        lB[q] = Bl + c * 8;
    }

    f32x4 acc[4][4];
#pragma unroll
    for (int m = 0; m < 4; m++)
#pragma unroll
        for (int n = 0; n < 4; n++) acc[m][n] = zero4();

    for (int k0 = 0; k0 < K; k0 += BK) {
        __syncthreads();
#pragma unroll
        for (int q = 0; q < 4; q++) {
            gload16(gA[q] + k0, lA[q]);
            gload16(gB[q] + k0, lB[q]);
        }
        __syncthreads();
#pragma unroll
        for (int ks = 0; ks < 2; ks++) {
            u16x8 af[4], bfr[4];
#pragma unroll
            for (int m = 0; m < 4; m++)
                af[m] = *(const u16x8*)&Al[(wr * 64 + m * 16 + l15) * BK + ks * 32 + l16 * 8];
#pragma unroll
            for (int n = 0; n < 4; n++)
                bfr[n] = *(const u16x8*)&Bl[(wc * 64 + n * 16 + l15) * BK + ks * 32 + l16 * 8];
#pragma unroll
            for (int m = 0; m < 4; m++)
#pragma unroll
                for (int n = 0; n < 4; n++) acc[m][n] = mfma16(af[m], bfr[n], acc[m][n]);
        }
    }

#pragma unroll
    for (int m = 0; m < 4; m++) {
#pragma unroll
        for (int j = 0; j < 4; j++) {
            int row = by * 128 + wr * 64 + m * 16 + l16 * 4 + j;
#pragma unroll
            for (int n = 0; n < 4; n++) {
                int col = bx * 128 + wc * 64 + n * 16 + l15;
                float val = acc[m][n][j];
                if constexpr (EPI == 0) {
                    int chunk = col >> 10, h = (col >> 6) & 15, d = col & 63;
                    int t = row >> 2, bI = row & 3;
                    if (chunk == 0) val *= 0.18033688011112042f;  // 0.125*log2(e)
                    u16* dst = (chunk == 0) ? qo : (chunk == 1) ? ko : vo;
                    dst[((size_t)(bI * 16 + h) * 2048 + t) * 64 + d] = f2b(val);
                } else {
                    fo[(size_t)row * N + col] = val;
                }
            }
        }
    }
}

// ---------------------------------------------------------------- flash attention
// grid: (T/128, B*H). 4 waves/WG, 32 q-rows/wave, KVBLK=64 key tiles (32 iters).
// Scores in exp2 domain. V staged [db=4][key=64][dlo=16]; db plane = 2048 B.
// Single lgkm drain per PV cluster; setprio around MFMA blocks.
__global__ __launch_bounds__(256, 3)
void attn_kernel(const u16* __restrict__ Qg, const u16* __restrict__ Kg,
                 const u16* __restrict__ Vg, const void* __restrict__ maskp,
                 const int* __restrict__ flag, u16* __restrict__ ctx) {
    __shared__ __align__(16) u16 Kl[64 * 72];      // [key][d] stride 72 (18432 B)
    __shared__ __align__(128) u16 Vs[4][64][16];   // [db][key][dlo]     (8192 B)
    __shared__ __align__(16) u16 Pl[4][32 * 72];   // per-wave P [q][key] (18432 B)

    int tid = threadIdx.x;
    int wave = tid >> 6, lane = tid & 63;
    int l15 = lane & 15, l16 = lane >> 4;
    int bh = blockIdx.y;
    int b = bh >> 4, h = bh & 15;
    size_t base = (size_t)bh * 2048 * 64;
    int q0 = blockIdx.x * 128 + wave * 32;

    int isInt = *flag;
    const unsigned char* m8 = (const unsigned char*)maskp;
    const int* m32 = (const int*)maskp;

    u16x8 aq[2][2];
#pragma unroll
    for (int qb = 0; qb < 2; qb++)
#pragma unroll
        for (int ks = 0; ks < 2; ks++)
            aq[qb][ks] = *(const u16x8*)(Qg + base + (size_t)(q0 + qb * 16 + l15) * 64 +
                                         ks * 32 + l16 * 8);

    f32x4 acc_o[2][4];
    float mrun[2][4], plsum[2][4];
#pragma unroll
    for (int qb = 0; qb < 2; qb++) {
#pragma unroll
        for (int db = 0; db < 4; db++) acc_o[qb][db] = zero4();
#pragma unroll
        for (int j = 0; j < 4; j++) { mrun[qb][j] = -1e30f; plsum[qb][j] = 0.f; }
    }

    // staging: thread -> K/V row srow2 (0..63), 16-elem d-chunk sc2 (0..3)
    int srow2 = tid >> 2, sc2 = tid & 3;
    const u16* kg2 = Kg + base + (size_t)srow2 * 64 + sc2 * 16;
    const u16* vg2 = Vg + base + (size_t)srow2 * 64 + sc2 * 16;
    u16* kld = &Kl[srow2 * 72 + sc2 * 16];
    u16* vsd = &Vs[sc2][srow2][0];                 // d-chunk 16 == one db: 32B contig
    unsigned vtrb = (unsigned)(uintptr_t)(&Vs[0][0][0]) + (unsigned)(l16 * 256 + l15 * 8);

    u16x8 ka = *(const u16x8*)kg2, kb_ = *(const u16x8*)(kg2 + 8);
    u16x8 va = *(const u16x8*)vg2, vb_ = *(const u16x8*)(vg2 + 8);

    for (int it = 0; it < 32; ++it) {
        int s0 = it * 64;
        __syncthreads();                  // prior tile's LDS reads done
        *(u16x8*)kld = ka; *(u16x8*)(kld + 8) = kb_;
        *(u16x8*)vsd = va; *(u16x8*)(vsd + 8) = vb_;
        int snext = (s0 + 64) & 2047;     // wraps on last iter (harmless)
        u16x8 kan = *(const u16x8*)(kg2 + (size_t)snext * 64);   // T14: in flight
        u16x8 kbn = *(const u16x8*)(kg2 + (size_t)snext * 64 + 8);
        u16x8 van = *(const u16x8*)(vg2 + (size_t)snext * 64);
        u16x8 vbn = *(const u16x8*)(vg2 + (size_t)snext * 64 + 8);
        __syncthreads();                  // staged tile visible

        int pad[4];
#pragma unroll
        for (int kb2 = 0; kb2 < 4; kb2++) {
            int ki = b * 2048 + s0 + kb2 * 16 + l15;
            pad[kb2] = isInt ? (m32[ki] != 0) : (m8[ki] != 0);
        }

        // S = Q * K^T (exp2 domain): 8 ds_read_b128 + 16 MFMA
        f32x4 sa[2][4];
#pragma unroll
        for (int kb2 = 0; kb2 < 4; kb2++) { sa[0][kb2] = zero4(); sa[1][kb2] = zero4(); }
        __builtin_amdgcn_s_setprio(1);
#pragma unroll
        for (int kb2 = 0; kb2 < 4; kb2++)
#pragma unroll
            for (int ks = 0; ks < 2; ks++) {
                u16x8 bk = *(const u16x8*)&Kl[(kb2 * 16 + l15) * 72 + ks * 32 + l16 * 8];
                sa[0][kb2] = mfma16(aq[0][ks], bk, sa[0][kb2]);
                sa[1][kb2] = mfma16(aq[1][ks], bk, sa[1][kb2]);
            }
        __builtin_amdgcn_s_setprio(0);

        // lazy-max online softmax (T13 thr=8: P bounded by 2^8)
#pragma unroll
        for (int qb = 0; qb < 2; qb++) {
            float sv[4][4];
            float gl = -1e30f;
#pragma unroll
            for (int kb2 = 0; kb2 < 4; kb2++)
#pragma unroll
                for (int j = 0; j < 4; j++) {
                    sv[kb2][j] = pad[kb2] ? -1e30f : sa[qb][kb2][j];
                    gl = fmaxf(gl, sv[kb2][j] - mrun[qb][j]);
                }
            if (__any(gl > 8.0f)) {
                float tm[4];
#pragma unroll
                for (int j = 0; j < 4; j++)
                    tm[j] = fmaxf(fmaxf(sv[0][j], sv[1][j]), fmaxf(sv[2][j], sv[3][j]));
#pragma unroll
                for (int j = 0; j < 4; j++) {
                    tm[j] = fmaxf(tm[j], __shfl_xor(tm[j], 1));
                    tm[j] = fmaxf(tm[j], __shfl_xor(tm[j], 2));
                    tm[j] = fmaxf(tm[j], __shfl_xor(tm[j], 4));
                    tm[j] = fmaxf(tm[j], __shfl_xor(tm[j], 8));
                }
#pragma unroll
                for (int j = 0; j < 4; j++) {
                    float mnew = fmaxf(mrun[qb][j], tm[j]);
                    float sc = exp2f(mrun[qb][j] - mnew);
                    mrun[qb][j] = mnew;
                    plsum[qb][j] *= sc;
#pragma unroll
                    for (int db = 0; db < 4; db++) acc_o[qb][db][j] *= sc;
                }
            }
#pragma unroll
            for (int j = 0; j < 4; j++) {
                int prow = qb * 16 + l16 * 4 + j;
                float ps = 0.f;
#pragma unroll
                for (int kb2 = 0; kb2 < 4; kb2++) {
                    float p = exp2f(sv[kb2][j] - mrun[qb][j]);
                    Pl[wave][prow * 72 + kb2 * 16 + l15] = f2b(p);
                    ps += p;
                }
                plsum[qb][j] += ps;
            }
        }

        // O += P * V: issue all P-frag + tr reads, one drain, 16 MFMA.
        // Vs db plane = 64*16*2 = 2048 B; window(db,ks2,l16) = db*2048 + ks2*1024
        // + l16*256; slot = l15*8; second read +128 B (keys +4).
        u16x8 ap[2][2];
#pragma unroll
        for (int qb = 0; qb < 2; qb++)
#pragma unroll
            for (int ks2 = 0; ks2 < 2; ks2++)
                ap[qb][ks2] = *(const u16x8*)&Pl[wave][(qb * 16 + l15) * 72 +
                                                       ks2 * 32 + l16 * 8];
        u16x4 t[4][2][2];
#pragma unroll
        for (int ks2 = 0; ks2 < 2; ks2++)
#pragma unroll
            for (int db = 0; db < 4; db++) {
                t[db][ks2][0] = tr16(vtrb + db * 2048 + ks2 * 1024);
                t[db][ks2][1] = tr16(vtrb + db * 2048 + ks2 * 1024 + 128);
            }
        asm volatile("s_waitcnt lgkmcnt(0)" ::: "memory");
        __builtin_amdgcn_sched_barrier(0);        // rule #18
        __builtin_amdgcn_s_setprio(1);
#pragma unroll
        for (int ks2 = 0; ks2 < 2; ks2++)
#pragma unroll
            for (int db = 0; db < 4; db++) {
                u16x8 bv = {t[db][ks2][0][0], t[db][ks2][0][1], t[db][ks2][0][2],
                            t[db][ks2][0][3], t[db][ks2][1][0], t[db][ks2][1][1],
                            t[db][ks2][1][2], t[db][ks2][1][3]};
                acc_o[0][db] = mfma16(ap[0][ks2], bv, acc_o[0][db]);
                acc_o[1][db] = mfma16(ap[1][ks2], bv, acc_o[1][db]);
            }
        __builtin_amdgcn_s_setprio(0);
        ka = kan; kb_ = kbn; va = van; vb_ = vbn;
    }

    // epilogue: reduce row sums once, then ctx[(t*4+b)*1024 + h*64 + d]
#pragma unroll
    for (int qb = 0; qb < 2; qb++)
#pragma unroll
        for (int j = 0; j < 4; j++) {
            float rs = plsum[qb][j];
            rs += __shfl_xor(rs, 1);
            rs += __shfl_xor(rs, 2);
            rs += __shfl_xor(rs, 4);
            rs += __shfl_xor(rs, 8);
            float inv = 1.0f / rs;
            int qg = q0 + qb * 16 + l16 * 4 + j;
            size_t mrow = (size_t)qg * 4 + b;
#pragma unroll
            for (int db = 0; db < 4; db++)
                ctx[mrow * 1024 + h * 64 + db * 16 + l15] = f2b(acc_o[qb][db][j] * inv);
        }
}

// ---------------------------------------------------------------- launch
extern "C" void kernel_launch(void* const* d_in, const int* in_sizes, int n_in,
                              void* d_out, int out_size, void* d_ws, size_t ws_size,
                              hipStream_t stream) {
    const float* x = (const float*)d_in[0];
    const float* wqkv = (const float*)d_in[1];
    const float* wo = (const float*)d_in[2];
    const void* mask = d_in[3];
    float* out = (float*)d_out;

    char* ws = (char*)d_ws;
    int* flag = (int*)ws;                       // 16 B
    u16* xb = (u16*)(ws + 16);                  // 8388608 elems (reused as ctx later)
    u16* wqkvb = xb + 8388608;                  // 3145728
    u16* wob = wqkvb + 3145728;                 // 1048576
    u16* qw = wob + 1048576;                    // 8388608
    u16* kw = qw + 8388608;                     // 8388608
    u16* vw = kw + 8388608;                     // 8388608
    u16* ctx = xb;                              // reuse after GEMM1

    cvt_bf16_kernel<<<8192, 256, 0, stream>>>(x, xb, 8388608);
    cvt_bf16_kernel<<<3072, 256, 0, stream>>>(wqkv, wqkvb, 3145728);
    cvt_bf16_kernel<<<1024, 256, 0, stream>>>(wo, wob, 1048576);
    detect_mask_kernel<<<1, 256, 0, stream>>>((const unsigned char*)mask, flag);

    gemm_bt_kernel<0><<<dim3(24, 64), 256, 0, stream>>>(xb, wqkvb, 8192, 3072, 1024,
                                                        qw, kw, vw, nullptr);
    attn_kernel<<<dim3(16, 64), 256, 0, stream>>>(qw, kw, vw, mask, flag, ctx);
    gemm_bt_kernel<1><<<dim3(8, 64), 256, 0, stream>>>(ctx, wob, 8192, 1024, 1024,
                                                       nullptr, nullptr, nullptr, out);
}

// Round 11
// 411.647 us; speedup vs baseline: 1.5204x; 1.0063x over previous
//
#include <hip/hip_runtime.h>

typedef unsigned short u16;
typedef __bf16 bf16x8 __attribute__((ext_vector_type(8)));
typedef unsigned short u16x8 __attribute__((ext_vector_type(8)));
typedef unsigned short u16x4 __attribute__((ext_vector_type(4)));
typedef float f32x4 __attribute__((ext_vector_type(4)));

__device__ __forceinline__ f32x4 mfma16(u16x8 a, u16x8 b, f32x4 c) {
    return __builtin_amdgcn_mfma_f32_16x16x32_bf16(
        __builtin_bit_cast(bf16x8, a), __builtin_bit_cast(bf16x8, b), c, 0, 0, 0);
}

// fp32 -> bf16 RNE
__device__ __forceinline__ u16 f2b(float f) {
    unsigned int u = __builtin_bit_cast(unsigned int, f);
    return (u16)((u + 0x7fffu + ((u >> 16) & 1u)) >> 16);
}

__device__ __forceinline__ f32x4 zero4() { f32x4 z = {0.f, 0.f, 0.f, 0.f}; return z; }

// async global->LDS direct copy, 16B per lane (m97 recipe)
typedef __attribute__((address_space(1))) const unsigned int gas_u32;
typedef __attribute__((address_space(3))) unsigned int las_u32;
__device__ __forceinline__ void gload16(const u16* g, u16* l) {
    __builtin_amdgcn_global_load_lds((gas_u32*)g, (las_u32*)l, 16, 0, 0);
}

// LDS HW-transpose read (Model B, validated round 8): addr selects a 128B
// window (addr & ~127) and 8B slot s=(addr&127)>>3; lane gets column s of the
// window viewed as 4x16 row-major bf16: elem j = window + 2*s + 32*j.
__device__ __forceinline__ u16x4 tr16(unsigned off) {
    u16x4 r;
    asm volatile("ds_read_b64_tr_b16 %0, %1" : "=v"(r) : "v"(off));
    return r;
}

// ---------------------------------------------------------------- converts
__global__ __launch_bounds__(256) void cvt_bf16_kernel(const float* __restrict__ in,
                                                       u16* __restrict__ out, int n) {
    int i = (blockIdx.x * 256 + threadIdx.x) * 4;
    if (i >= n) return;
    float4 v = *reinterpret_cast<const float4*>(in + i);
    u16x4 o;
    o.x = f2b(v.x); o.y = f2b(v.y); o.z = f2b(v.z); o.w = f2b(v.w);
    *reinterpret_cast<u16x4*>(out + i) = o;
}

// ------------------------------------------------- mask storage detection
__global__ void detect_mask_kernel(const unsigned char* __restrict__ m, int* __restrict__ flag) {
    __shared__ int any;
    if (threadIdx.x == 0) any = 0;
    __syncthreads();
    int acc = 0;
    for (int i = threadIdx.x; i < 8192; i += 256)
        if (i & 3) acc |= m[i];
    if (acc) atomicOr(&any, 1);
    __syncthreads();
    if (threadIdx.x == 0) *flag = any ? 0 : 1;
}

// ---------------------------------------------------------------- GEMM C = A * B^T
// m97-exact: 128x128 tile, BK=64, 4 waves (2x2), 4x4 frags, global_load_lds w16,
// 2 barriers per 64-K step. XCD-swizzled tile ids (grid%8==0 -> bijective).
// EPI 0: scatter Q(*0.125*log2e)/K/V. EPI 1: fp32 out.
template <int EPI>
__global__ __launch_bounds__(256)
void gemm_bt_kernel(const u16* __restrict__ A, const u16* __restrict__ Bt,
                    int M, int N, int K,
                    u16* __restrict__ qo, u16* __restrict__ ko, u16* __restrict__ vo,
                    float* __restrict__ fo) {
    constexpr int BK = 64;
    __shared__ __align__(16) u16 Al[128 * BK];
    __shared__ __align__(16) u16 Bl[128 * BK];
    int tid = threadIdx.x;
    int wave = tid >> 6, lane = tid & 63;
    int l15 = lane & 15, l16 = lane >> 4;
    int wr = wave >> 1, wc = wave & 1;

    // XCD swizzle: contiguous tile chunk per XCD (T1)
    int flat = blockIdx.y * gridDim.x + blockIdx.x;
    int nwg = gridDim.x * gridDim.y;
    int swz = (flat & 7) * (nwg >> 3) + (flat >> 3);
    int bx = swz % gridDim.x, by = swz / gridDim.x;

    const u16* gA[4]; const u16* gB[4]; u16* lA[4]; u16* lB[4];
#pragma unroll
    for (int q = 0; q < 4; q++) {
        int c = tid + q * 256;
        gA[q] = A + (size_t)(by * 128 + (c >> 3)) * K + (c & 7) * 8;
        gB[q] = Bt + (size_t)(bx * 128 + (c >> 3)) * K + (c & 7) * 8;
        lA[q] = Al + c * 8;
        lB[q] = Bl + c * 8;
    }

    f32x4 acc[4][4];
#pragma unroll
    for (int m = 0; m < 4; m++)
#pragma unroll
        for (int n = 0; n < 4; n++) acc[m][n] = zero4();

    for (int k0 = 0; k0 < K; k0 += BK) {
        __syncthreads();
#pragma unroll
        for (int q = 0; q < 4; q++) {
            gload16(gA[q] + k0, lA[q]);
            gload16(gB[q] + k0, lB[q]);
        }
        __syncthreads();
#pragma unroll
        for (int ks = 0; ks < 2; ks++) {
            u16x8 af[4], bfr[4];
#pragma unroll
            for (int m = 0; m < 4; m++)
                af[m] = *(const u16x8*)&Al[(wr * 64 + m * 16 + l15) * BK + ks * 32 + l16 * 8];
#pragma unroll
            for (int n = 0; n < 4; n++)
                bfr[n] = *(const u16x8*)&Bl[(wc * 64 + n * 16 + l15) * BK + ks * 32 + l16 * 8];
#pragma unroll
            for (int m = 0; m < 4; m++)
#pragma unroll
                for (int n = 0; n < 4; n++) acc[m][n] = mfma16(af[m], bfr[n], acc[m][n]);
        }
    }

#pragma unroll
    for (int m = 0; m < 4; m++) {
#pragma unroll
        for (int j = 0; j < 4; j++) {
            int row = by * 128 + wr * 64 + m * 16 + l16 * 4 + j;
#pragma unroll
            for (int n = 0; n < 4; n++) {
                int col = bx * 128 + wc * 64 + n * 16 + l15;
                float val = acc[m][n][j];
                if constexpr (EPI == 0) {
                    int chunk = col >> 10, h = (col >> 6) & 15, d = col & 63;
                    int t = row >> 2, bI = row & 3;
                    if (chunk == 0) val *= 0.18033688011112042f;  // 0.125*log2(e)
                    u16* dst = (chunk == 0) ? qo : (chunk == 1) ? ko : vo;
                    dst[((size_t)(bI * 16 + h) * 2048 + t) * 64 + d] = f2b(val);
                } else {
                    fo[(size_t)row * N + col] = val;
                }
            }
        }
    }
}

// ---------------------------------------------------------------- flash attention
// grid: (T/128, B*H), XCD-swizzled. 4 waves/WG, 32 q-rows/wave, KVBLK=64 (32 iters).
// Scores in exp2 domain. Key-position permutation: within each 32-key chunk,
// position q = (key&15)*2 + ((key>>4)&1) -- lets P-stores be packed b32 writes;
// V is staged to matching positions so PV (sum over keys) is invariant.
__global__ __launch_bounds__(256, 3)
void attn_kernel(const u16* __restrict__ Qg, const u16* __restrict__ Kg,
                 const u16* __restrict__ Vg, const void* __restrict__ maskp,
                 const int* __restrict__ flag, u16* __restrict__ ctx) {
    __shared__ __align__(16) u16 Kl[64 * 72];      // [key][d] stride 72 (18432 B)
    __shared__ __align__(128) u16 Vs[4][64][16];   // [db][pos][dlo]     (8192 B)
    __shared__ __align__(16) u16 Pl[4][32 * 72];   // per-wave P [q][pos] (18432 B)

    int tid = threadIdx.x;
    int wave = tid >> 6, lane = tid & 63;
    int l15 = lane & 15, l16 = lane >> 4;

    int flat = blockIdx.y * gridDim.x + blockIdx.x;
    int nwg = gridDim.x * gridDim.y;
    int swz = (flat & 7) * (nwg >> 3) + (flat >> 3);
    int bxs = swz & 15, bh = swz >> 4;

    int b = bh >> 4, h = bh & 15;
    size_t base = (size_t)bh * 2048 * 64;
    int q0 = bxs * 128 + wave * 32;

    int isInt = *flag;
    const unsigned char* m8 = (const unsigned char*)maskp;
    const int* m32 = (const int*)maskp;

    u16x8 aq[2][2];
#pragma unroll
    for (int qb = 0; qb < 2; qb++)
#pragma unroll
        for (int ks = 0; ks < 2; ks++)
            aq[qb][ks] = *(const u16x8*)(Qg + base + (size_t)(q0 + qb * 16 + l15) * 64 +
                                         ks * 32 + l16 * 8);

    f32x4 acc_o[2][4];
    float mrun[2][4], plsum[2][4];
#pragma unroll
    for (int qb = 0; qb < 2; qb++) {
#pragma unroll
        for (int db = 0; db < 4; db++) acc_o[qb][db] = zero4();
#pragma unroll
        for (int j = 0; j < 4; j++) { mrun[qb][j] = -1e30f; plsum[qb][j] = 0.f; }
    }

    // staging: thread -> K/V row srow2 (0..63), 16-elem d-chunk sc2 (0..3)
    int srow2 = tid >> 2, sc2 = tid & 3;
    const u16* kg2 = Kg + base + (size_t)srow2 * 64 + sc2 * 16;
    const u16* vg2 = Vg + base + (size_t)srow2 * 64 + sc2 * 16;
    u16* kld = &Kl[srow2 * 72 + sc2 * 16];
    // permuted V position: P = (key>>5)*32 + (key&15)*2 + ((key>>4)&1)
    int vpos = ((srow2 >> 5) << 5) + ((srow2 & 15) * 2) + ((srow2 >> 4) & 1);
    u16* vsd = &Vs[sc2][vpos][0];
    unsigned vtrb = (unsigned)(uintptr_t)(&Vs[0][0][0]) + (unsigned)(l16 * 256 + l15 * 8);

    u16x8 ka = *(const u16x8*)kg2, kb_ = *(const u16x8*)(kg2 + 8);
    u16x8 va = *(const u16x8*)vg2, vb_ = *(const u16x8*)(vg2 + 8);

    for (int it = 0; it < 32; ++it) {
        int s0 = it * 64;
        __syncthreads();                  // prior tile's LDS reads done
        *(u16x8*)kld = ka; *(u16x8*)(kld + 8) = kb_;
        *(u16x8*)vsd = va; *(u16x8*)(vsd + 8) = vb_;
        int snext = (s0 + 64) & 2047;     // wraps on last iter (harmless)
        u16x8 kan = *(const u16x8*)(kg2 + (size_t)snext * 64);   // T14: in flight
        u16x8 kbn = *(const u16x8*)(kg2 + (size_t)snext * 64 + 8);
        u16x8 van = *(const u16x8*)(vg2 + (size_t)snext * 64);
        u16x8 vbn = *(const u16x8*)(vg2 + (size_t)snext * 64 + 8);
        __syncthreads();                  // staged tile visible

        int pad[4];
#pragma unroll
        for (int kb2 = 0; kb2 < 4; kb2++) {
            int ki = b * 2048 + s0 + kb2 * 16 + l15;
            pad[kb2] = isInt ? (m32[ki] != 0) : (m8[ki] != 0);
        }

        // S = Q * K^T (exp2 domain): 8 ds_read_b128 + 16 MFMA
        f32x4 sa[2][4];
#pragma unroll
        for (int kb2 = 0; kb2 < 4; kb2++) { sa[0][kb2] = zero4(); sa[1][kb2] = zero4(); }
        __builtin_amdgcn_s_setprio(1);
#pragma unroll
        for (int kb2 = 0; kb2 < 4; kb2++)
#pragma unroll
            for (int ks = 0; ks < 2; ks++) {
                u16x8 bk = *(const u16x8*)&Kl[(kb2 * 16 + l15) * 72 + ks * 32 + l16 * 8];
                sa[0][kb2] = mfma16(aq[0][ks], bk, sa[0][kb2]);
                sa[1][kb2] = mfma16(aq[1][ks], bk, sa[1][kb2]);
            }
        __builtin_amdgcn_s_setprio(0);

        // lazy-max online softmax (T13 thr=8: P bounded by 2^8)
#pragma unroll
        for (int qb = 0; qb < 2; qb++) {
            float sv[4][4];
            float gl = -1e30f;
#pragma unroll
            for (int kb2 = 0; kb2 < 4; kb2++)
#pragma unroll
                for (int j = 0; j < 4; j++) {
                    sv[kb2][j] = pad[kb2] ? -1e30f : sa[qb][kb2][j];
                    gl = fmaxf(gl, sv[kb2][j] - mrun[qb][j]);
                }
            if (__any(gl > 8.0f)) {
                float tm[4];
#pragma unroll
                for (int j = 0; j < 4; j++)
                    tm[j] = fmaxf(fmaxf(sv[0][j], sv[1][j]), fmaxf(sv[2][j], sv[3][j]));
#pragma unroll
                for (int j = 0; j < 4; j++) {
                    tm[j] = fmaxf(tm[j], __shfl_xor(tm[j], 1));
                    tm[j] = fmaxf(tm[j], __shfl_xor(tm[j], 2));
                    tm[j] = fmaxf(tm[j], __shfl_xor(tm[j], 4));
                    tm[j] = fmaxf(tm[j], __shfl_xor(tm[j], 8));
                }
#pragma unroll
                for (int j = 0; j < 4; j++) {
                    float mnew = fmaxf(mrun[qb][j], tm[j]);
                    float sc = exp2f(mrun[qb][j] - mnew);
                    mrun[qb][j] = mnew;
                    plsum[qb][j] *= sc;
#pragma unroll
                    for (int db = 0; db < 4; db++) acc_o[qb][db][j] *= sc;
                }
            }
            // packed P stores: pair (kb2=2c, 2c+1) -> one b32 at pos c*32 + l15*2
#pragma unroll
            for (int j = 0; j < 4; j++) {
                int prow = qb * 16 + l16 * 4 + j;
                float p0 = exp2f(sv[0][j] - mrun[qb][j]);
                float p1 = exp2f(sv[1][j] - mrun[qb][j]);
                float p2 = exp2f(sv[2][j] - mrun[qb][j]);
                float p3 = exp2f(sv[3][j] - mrun[qb][j]);
                unsigned w01 = (unsigned)f2b(p0) | ((unsigned)f2b(p1) << 16);
                unsigned w23 = (unsigned)f2b(p2) | ((unsigned)f2b(p3) << 16);
                *(unsigned*)&Pl[wave][prow * 72 + l15 * 2] = w01;
                *(unsigned*)&Pl[wave][prow * 72 + 32 + l15 * 2] = w23;
                plsum[qb][j] += (p0 + p1) + (p2 + p3);
            }
        }

        // O += P * V: all reads issued, one drain, 16 MFMA (positions match V)
        u16x8 ap[2][2];
#pragma unroll
        for (int qb = 0; qb < 2; qb++)
#pragma unroll
            for (int ks2 = 0; ks2 < 2; ks2++)
                ap[qb][ks2] = *(const u16x8*)&Pl[wave][(qb * 16 + l15) * 72 +
                                                       ks2 * 32 + l16 * 8];
        u16x4 t[4][2][2];
#pragma unroll
        for (int ks2 = 0; ks2 < 2; ks2++)
#pragma unroll
            for (int db = 0; db < 4; db++) {
                t[db][ks2][0] = tr16(vtrb + db * 2048 + ks2 * 1024);
                t[db][ks2][1] = tr16(vtrb + db * 2048 + ks2 * 1024 + 128);
            }
        asm volatile("s_waitcnt lgkmcnt(0)" ::: "memory");
        __builtin_amdgcn_sched_barrier(0);        // rule #18
        __builtin_amdgcn_s_setprio(1);
#pragma unroll
        for (int ks2 = 0; ks2 < 2; ks2++)
#pragma unroll
            for (int db = 0; db < 4; db++) {
                u16x8 bv = {t[db][ks2][0][0], t[db][ks2][0][1], t[db][ks2][0][2],
                            t[db][ks2][0][3], t[db][ks2][1][0], t[db][ks2][1][1],
                            t[db][ks2][1][2], t[db][ks2][1][3]};
                acc_o[0][db] = mfma16(ap[0][ks2], bv, acc_o[0][db]);
                acc_o[1][db] = mfma16(ap[1][ks2], bv, acc_o[1][db]);
            }
        __builtin_amdgcn_s_setprio(0);
        ka = kan; kb_ = kbn; va = van; vb_ = vbn;
    }

    // epilogue: reduce row sums once, then ctx[(t*4+b)*1024 + h*64 + d]
#pragma unroll
    for (int qb = 0; qb < 2; qb++)
#pragma unroll
        for (int j = 0; j < 4; j++) {
            float rs = plsum[qb][j];
            rs += __shfl_xor(rs, 1);
            rs += __shfl_xor(rs, 2);
            rs += __shfl_xor(rs, 4);
            rs += __shfl_xor(rs, 8);
            float inv = 1.0f / rs;
            int qg = q0 + qb * 16 + l16 * 4 + j;
            size_t mrow = (size_t)qg * 4 + b;
#pragma unroll
            for (int db = 0; db < 4; db++)
                ctx[mrow * 1024 + h * 64 + db * 16 + l15] = f2b(acc_o[qb][db][j] * inv);
        }
}

// ---------------------------------------------------------------- launch
extern "C" void kernel_launch(void* const* d_in, const int* in_sizes, int n_in,
                              void* d_out, int out_size, void* d_ws, size_t ws_size,
                              hipStream_t stream) {
    const float* x = (const float*)d_in[0];
    const float* wqkv = (const float*)d_in[1];
    const float* wo = (const float*)d_in[2];
    const void* mask = d_in[3];
    float* out = (float*)d_out;

    char* ws = (char*)d_ws;
    int* flag = (int*)ws;                       // 16 B
    u16* xb = (u16*)(ws + 16);                  // 8388608 elems (reused as ctx later)
    u16* wqkvb = xb + 8388608;                  // 3145728
    u16* wob = wqkvb + 3145728;                 // 1048576
    u16* qw = wob + 1048576;                    // 8388608
    u16* kw = qw + 8388608;                     // 8388608
    u16* vw = kw + 8388608;                     // 8388608
    u16* ctx = xb;                              // reuse after GEMM1

    cvt_bf16_kernel<<<8192, 256, 0, stream>>>(x, xb, 8388608);
    cvt_bf16_kernel<<<3072, 256, 0, stream>>>(wqkv, wqkvb, 3145728);
    cvt_bf16_kernel<<<1024, 256, 0, stream>>>(wo, wob, 1048576);
    detect_mask_kernel<<<1, 256, 0, stream>>>((const unsigned char*)mask, flag);

    gemm_bt_kernel<0><<<dim3(24, 64), 256, 0, stream>>>(xb, wqkvb, 8192, 3072, 1024,
                                                        qw, kw, vw, nullptr);
    attn_kernel<<<dim3(16, 64), 256, 0, stream>>>(qw, kw, vw, mask, flag, ctx);
    gemm_bt_kernel<1><<<dim3(8, 64), 256, 0, stream>>>(ctx, wob, 8192, 1024, 1024,
                                                       nullptr, nullptr, nullptr, out);
}

// Round 13
// 403.002 us; speedup vs baseline: 1.5530x; 1.0215x over previous
//
#include <hip/hip_runtime.h>

typedef unsigned short u16;
typedef __bf16 bf16x8 __attribute__((ext_vector_type(8)));
typedef unsigned short u16x8 __attribute__((ext_vector_type(8)));
typedef unsigned short u16x4 __attribute__((ext_vector_type(4)));
typedef float f32x4 __attribute__((ext_vector_type(4)));

__device__ __forceinline__ f32x4 mfma16(u16x8 a, u16x8 b, f32x4 c) {
    return __builtin_amdgcn_mfma_f32_16x16x32_bf16(
        __builtin_bit_cast(bf16x8, a), __builtin_bit_cast(bf16x8, b), c, 0, 0, 0);
}

// fp32 -> bf16 RNE
__device__ __forceinline__ u16 f2b(float f) {
    unsigned int u = __builtin_bit_cast(unsigned int, f);
    return (u16)((u + 0x7fffu + ((u >> 16) & 1u)) >> 16);
}

// two f32 -> packed bf16 pair (low=a, high=b), RNE — one VALU instr (T12)
__device__ __forceinline__ unsigned cvtpk(float a, float b) {
    unsigned r;
    asm("v_cvt_pk_bf16_f32 %0, %1, %2" : "=v"(r) : "v"(a), "v"(b));
    return r;
}

__device__ __forceinline__ f32x4 zero4() { f32x4 z = {0.f, 0.f, 0.f, 0.f}; return z; }

// async global->LDS direct copy, 16B per lane (m97 recipe)
typedef __attribute__((address_space(1))) const unsigned int gas_u32;
typedef __attribute__((address_space(3))) unsigned int las_u32;
__device__ __forceinline__ void gload16(const u16* g, u16* l) {
    __builtin_amdgcn_global_load_lds((gas_u32*)g, (las_u32*)l, 16, 0, 0);
}

// LDS HW-transpose read (Model B, validated round 8): addr selects a 128B
// window (addr & ~127) and 8B slot s=(addr&127)>>3; lane gets column s of the
// window viewed as 4x16 row-major bf16: elem j = window + 2*s + 32*j.
__device__ __forceinline__ u16x4 tr16(unsigned off) {
    u16x4 r;
    asm volatile("ds_read_b64_tr_b16 %0, %1" : "=v"(r) : "v"(off));
    return r;
}

// ---------------------------------------------------------------- converts
__global__ __launch_bounds__(256) void cvt_bf16_kernel(const float* __restrict__ in,
                                                       u16* __restrict__ out, int n) {
    int i = (blockIdx.x * 256 + threadIdx.x) * 4;
    if (i >= n) return;
    float4 v = *reinterpret_cast<const float4*>(in + i);
    u16x4 o;
    o.x = f2b(v.x); o.y = f2b(v.y); o.z = f2b(v.z); o.w = f2b(v.w);
    *reinterpret_cast<u16x4*>(out + i) = o;
}

// ------------------------------------------------- mask storage detection
__global__ void detect_mask_kernel(const unsigned char* __restrict__ m, int* __restrict__ flag) {
    __shared__ int any;
    if (threadIdx.x == 0) any = 0;
    __syncthreads();
    int acc = 0;
    for (int i = threadIdx.x; i < 8192; i += 256)
        if (i & 3) acc |= m[i];
    if (acc) atomicOr(&any, 1);
    __syncthreads();
    if (threadIdx.x == 0) *flag = any ? 0 : 1;
}

// ---------------------------------------------------------------- GEMM C = A * B^T
// m97-exact: 128x128 tile, BK=64, 4 waves (2x2), 4x4 frags, global_load_lds w16,
// 2 barriers per 64-K step. XCD-swizzled tile ids (grid%8==0 -> bijective).
// EPI 0: scatter Q(*0.125*log2e)/K/V. EPI 1: fp32 out.
template <int EPI>
__global__ __launch_bounds__(256)
void gemm_bt_kernel(const u16* __restrict__ A, const u16* __restrict__ Bt,
                    int M, int N, int K,
                    u16* __restrict__ qo, u16* __restrict__ ko, u16* __restrict__ vo,
                    float* __restrict__ fo) {
    constexpr int BK = 64;
    __shared__ __align__(16) u16 Al[128 * BK];
    __shared__ __align__(16) u16 Bl[128 * BK];
    int tid = threadIdx.x;
    int wave = tid >> 6, lane = tid & 63;
    int l15 = lane & 15, l16 = lane >> 4;
    int wr = wave >> 1, wc = wave & 1;

    // XCD swizzle: contiguous tile chunk per XCD (T1)
    int flat = blockIdx.y * gridDim.x + blockIdx.x;
    int nwg = gridDim.x * gridDim.y;
    int swz = (flat & 7) * (nwg >> 3) + (flat >> 3);
    int bx = swz % gridDim.x, by = swz / gridDim.x;

    const u16* gA[4]; const u16* gB[4]; u16* lA[4]; u16* lB[4];
#pragma unroll
    for (int q = 0; q < 4; q++) {
        int c = tid + q * 256;
        gA[q] = A + (size_t)(by * 128 + (c >> 3)) * K + (c & 7) * 8;
        gB[q] = Bt + (size_t)(bx * 128 + (c >> 3)) * K + (c & 7) * 8;
        lA[q] = Al + c * 8;
        lB[q] = Bl + c * 8;
    }

    f32x4 acc[4][4];
#pragma unroll
    for (int m = 0; m < 4; m++)
#pragma unroll
        for (int n = 0; n < 4; n++) acc[m][n] = zero4();

    for (int k0 = 0; k0 < K; k0 += BK) {
        __syncthreads();
#pragma unroll
        for (int q = 0; q < 4; q++) {
            gload16(gA[q] + k0, lA[q]);
            gload16(gB[q] + k0, lB[q]);
        }
        __syncthreads();
#pragma unroll
        for (int ks = 0; ks < 2; ks++) {
            u16x8 af[4], bfr[4];
#pragma unroll
            for (int m = 0; m < 4; m++)
                af[m] = *(const u16x8*)&Al[(wr * 64 + m * 16 + l15) * BK + ks * 32 + l16 * 8];
#pragma unroll
            for (int n = 0; n < 4; n++)
                bfr[n] = *(const u16x8*)&Bl[(wc * 64 + n * 16 + l15) * BK + ks * 32 + l16 * 8];
#pragma unroll
            for (int m = 0; m < 4; m++)
#pragma unroll
                for (int n = 0; n < 4; n++) acc[m][n] = mfma16(af[m], bfr[n], acc[m][n]);
        }
    }

#pragma unroll
    for (int m = 0; m < 4; m++) {
#pragma unroll
        for (int j = 0; j < 4; j++) {
            int row = by * 128 + wr * 64 + m * 16 + l16 * 4 + j;
#pragma unroll
            for (int n = 0; n < 4; n++) {
                int col = bx * 128 + wc * 64 + n * 16 + l15;
                float val = acc[m][n][j];
                if constexpr (EPI == 0) {
                    int chunk = col >> 10, h = (col >> 6) & 15, d = col & 63;
                    int t = row >> 2, bI = row & 3;
                    if (chunk == 0) val *= 0.18033688011112042f;  // 0.125*log2(e)
                    u16* dst = (chunk == 0) ? qo : (chunk == 1) ? ko : vo;
                    dst[((size_t)(bI * 16 + h) * 2048 + t) * 64 + d] = f2b(val);
                } else {
                    fo[(size_t)row * N + col] = val;
                }
            }
        }
    }
}

// ---------------------------------------------------------------- flash attention
// grid: (T/128, B*H), XCD-swizzled. 4 waves/WG, 32 q-rows/wave, KVBLK=64 (32 iters).
// Scores in exp2 domain. Key-position permutation: within each 32-key chunk,
// position q = (key&15)*2 + ((key>>4)&1) -- lets P-stores be packed b32 writes;
// V is staged to matching positions so PV (sum over keys) is invariant.
__global__ __launch_bounds__(256, 3)
void attn_kernel(const u16* __restrict__ Qg, const u16* __restrict__ Kg,
                 const u16* __restrict__ Vg, const void* __restrict__ maskp,
                 const int* __restrict__ flag, u16* __restrict__ ctx) {
    __shared__ __align__(16) u16 Kl[64 * 72];      // [key][d] stride 72 (18432 B)
    __shared__ __align__(128) u16 Vs[4][64][16];   // [db][pos][dlo]     (8192 B)
    __shared__ __align__(16) u16 Pl[4][32 * 72];   // per-wave P [q][pos] (18432 B)

    int tid = threadIdx.x;
    int wave = tid >> 6, lane = tid & 63;
    int l15 = lane & 15, l16 = lane >> 4;

    int flat = blockIdx.y * gridDim.x + blockIdx.x;
    int nwg = gridDim.x * gridDim.y;
    int swz = (flat & 7) * (nwg >> 3) + (flat >> 3);
    int bxs = swz & 15, bh = swz >> 4;

    int b = bh >> 4, h = bh & 15;
    size_t base = (size_t)bh * 2048 * 64;
    int q0 = bxs * 128 + wave * 32;

    int isInt = *flag;
    const unsigned char* m8 = (const unsigned char*)maskp;
    const int* m32 = (const int*)maskp;

    u16x8 aq[2][2];
#pragma unroll
    for (int qb = 0; qb < 2; qb++)
#pragma unroll
        for (int ks = 0; ks < 2; ks++)
            aq[qb][ks] = *(const u16x8*)(Qg + base + (size_t)(q0 + qb * 16 + l15) * 64 +
                                         ks * 32 + l16 * 8);

    f32x4 acc_o[2][4];
    float mrun[2][4], plsum[2][4];
#pragma unroll
    for (int qb = 0; qb < 2; qb++) {
#pragma unroll
        for (int db = 0; db < 4; db++) acc_o[qb][db] = zero4();
#pragma unroll
        for (int j = 0; j < 4; j++) { mrun[qb][j] = -1e30f; plsum[qb][j] = 0.f; }
    }

    // staging: thread -> K/V row srow2 (0..63), 16-elem d-chunk sc2 (0..3)
    int srow2 = tid >> 2, sc2 = tid & 3;
    const u16* kg2 = Kg + base + (size_t)srow2 * 64 + sc2 * 16;
    const u16* vg2 = Vg + base + (size_t)srow2 * 64 + sc2 * 16;
    u16* kld = &Kl[srow2 * 72 + sc2 * 16];
    // permuted V position: P = (key>>5)*32 + (key&15)*2 + ((key>>4)&1)
    int vpos = ((srow2 >> 5) << 5) + ((srow2 & 15) * 2) + ((srow2 >> 4) & 1);
    u16* vsd = &Vs[sc2][vpos][0];
    unsigned vtrb = (unsigned)(uintptr_t)(&Vs[0][0][0]) + (unsigned)(l16 * 256 + l15 * 8);

    u16x8 ka = *(const u16x8*)kg2, kb_ = *(const u16x8*)(kg2 + 8);
    u16x8 va = *(const u16x8*)vg2, vb_ = *(const u16x8*)(vg2 + 8);

    for (int it = 0; it < 32; ++it) {
        int s0 = it * 64;
        __syncthreads();                  // prior tile's LDS reads done
        *(u16x8*)kld = ka; *(u16x8*)(kld + 8) = kb_;
        *(u16x8*)vsd = va; *(u16x8*)(vsd + 8) = vb_;
        int snext = (s0 + 64) & 2047;     // wraps on last iter (harmless)
        u16x8 kan = *(const u16x8*)(kg2 + (size_t)snext * 64);   // T14: in flight
        u16x8 kbn = *(const u16x8*)(kg2 + (size_t)snext * 64 + 8);
        u16x8 van = *(const u16x8*)(vg2 + (size_t)snext * 64);
        u16x8 vbn = *(const u16x8*)(vg2 + (size_t)snext * 64 + 8);
        __syncthreads();                  // staged tile visible

        int pad[4];
#pragma unroll
        for (int kb2 = 0; kb2 < 4; kb2++) {
            int ki = b * 2048 + s0 + kb2 * 16 + l15;
            pad[kb2] = isInt ? (m32[ki] != 0) : (m8[ki] != 0);
        }

        // S = Q * K^T (exp2 domain): 8 ds_read_b128 + 16 MFMA
        f32x4 sa[2][4];
#pragma unroll
        for (int kb2 = 0; kb2 < 4; kb2++) { sa[0][kb2] = zero4(); sa[1][kb2] = zero4(); }
        __builtin_amdgcn_s_setprio(1);
#pragma unroll
        for (int kb2 = 0; kb2 < 4; kb2++)
#pragma unroll
            for (int ks = 0; ks < 2; ks++) {
                u16x8 bk = *(const u16x8*)&Kl[(kb2 * 16 + l15) * 72 + ks * 32 + l16 * 8];
                sa[0][kb2] = mfma16(aq[0][ks], bk, sa[0][kb2]);
                sa[1][kb2] = mfma16(aq[1][ks], bk, sa[1][kb2]);
            }
        __builtin_amdgcn_s_setprio(0);

        // lazy-max online softmax (T13 thr=8: P bounded by 2^8)
#pragma unroll
        for (int qb = 0; qb < 2; qb++) {
            float sv[4][4];
            float gl = -1e30f;
#pragma unroll
            for (int kb2 = 0; kb2 < 4; kb2++)
#pragma unroll
                for (int j = 0; j < 4; j++) {
                    sv[kb2][j] = pad[kb2] ? -1e30f : sa[qb][kb2][j];
                    gl = fmaxf(gl, sv[kb2][j] - mrun[qb][j]);
                }
            if (__any(gl > 8.0f)) {
                float tm[4];
#pragma unroll
                for (int j = 0; j < 4; j++)
                    tm[j] = fmaxf(fmaxf(sv[0][j], sv[1][j]), fmaxf(sv[2][j], sv[3][j]));
#pragma unroll
                for (int j = 0; j < 4; j++) {
                    tm[j] = fmaxf(tm[j], __shfl_xor(tm[j], 1));
                    tm[j] = fmaxf(tm[j], __shfl_xor(tm[j], 2));
                    tm[j] = fmaxf(tm[j], __shfl_xor(tm[j], 4));
                    tm[j] = fmaxf(tm[j], __shfl_xor(tm[j], 8));
                }
#pragma unroll
                for (int j = 0; j < 4; j++) {
                    float mnew = fmaxf(mrun[qb][j], tm[j]);
                    float sc = exp2f(mrun[qb][j] - mnew);
                    mrun[qb][j] = mnew;
                    plsum[qb][j] *= sc;
#pragma unroll
                    for (int db = 0; db < 4; db++) acc_o[qb][db][j] *= sc;
                }
            }
            // packed P stores via v_cvt_pk_bf16_f32 (2 instrs replace ~20 VALU)
#pragma unroll
            for (int j = 0; j < 4; j++) {
                int prow = qb * 16 + l16 * 4 + j;
                float p0 = exp2f(sv[0][j] - mrun[qb][j]);
                float p1 = exp2f(sv[1][j] - mrun[qb][j]);
                float p2 = exp2f(sv[2][j] - mrun[qb][j]);
                float p3 = exp2f(sv[3][j] - mrun[qb][j]);
                *(unsigned*)&Pl[wave][prow * 72 + l15 * 2] = cvtpk(p0, p1);
                *(unsigned*)&Pl[wave][prow * 72 + 32 + l15 * 2] = cvtpk(p2, p3);
                plsum[qb][j] += (p0 + p1) + (p2 + p3);
            }
        }

        // O += P * V: all reads issued, one drain, 16 MFMA (positions match V)
        u16x8 ap[2][2];
#pragma unroll
        for (int qb = 0; qb < 2; qb++)
#pragma unroll
            for (int ks2 = 0; ks2 < 2; ks2++)
                ap[qb][ks2] = *(const u16x8*)&Pl[wave][(qb * 16 + l15) * 72 +
                                                       ks2 * 32 + l16 * 8];
        u16x4 t[4][2][2];
#pragma unroll
        for (int ks2 = 0; ks2 < 2; ks2++)
#pragma unroll
            for (int db = 0; db < 4; db++) {
                t[db][ks2][0] = tr16(vtrb + db * 2048 + ks2 * 1024);
                t[db][ks2][1] = tr16(vtrb + db * 2048 + ks2 * 1024 + 128);
            }
        asm volatile("s_waitcnt lgkmcnt(0)" ::: "memory");
        __builtin_amdgcn_sched_barrier(0);        // rule #18
        __builtin_amdgcn_s_setprio(1);
#pragma unroll
        for (int ks2 = 0; ks2 < 2; ks2++)
#pragma unroll
            for (int db = 0; db < 4; db++) {
                u16x8 bv = {t[db][ks2][0][0], t[db][ks2][0][1], t[db][ks2][0][2],
                            t[db][ks2][0][3], t[db][ks2][1][0], t[db][ks2][1][1],
                            t[db][ks2][1][2], t[db][ks2][1][3]};
                acc_o[0][db] = mfma16(ap[0][ks2], bv, acc_o[0][db]);
                acc_o[1][db] = mfma16(ap[1][ks2], bv, acc_o[1][db]);
            }
        __builtin_amdgcn_s_setprio(0);
        ka = kan; kb_ = kbn; va = van; vb_ = vbn;
    }

    // epilogue: reduce row sums once, then ctx[(t*4+b)*1024 + h*64 + d]
#pragma unroll
    for (int qb = 0; qb < 2; qb++)
#pragma unroll
        for (int j = 0; j < 4; j++) {
            float rs = plsum[qb][j];
            rs += __shfl_xor(rs, 1);
            rs += __shfl_xor(rs, 2);
            rs += __shfl_xor(rs, 4);
            rs += __shfl_xor(rs, 8);
            float inv = 1.0f / rs;
            int qg = q0 + qb * 16 + l16 * 4 + j;
            size_t mrow = (size_t)qg * 4 + b;
#pragma unroll
            for (int db = 0; db < 4; db++)
                ctx[mrow * 1024 + h * 64 + db * 16 + l15] = f2b(acc_o[qb][db][j] * inv);
        }
}

// ---------------------------------------------------------------- launch
extern "C" void kernel_launch(void* const* d_in, const int* in_sizes, int n_in,
                              void* d_out, int out_size, void* d_ws, size_t ws_size,
                              hipStream_t stream) {
    const float* x = (const float*)d_in[0];
    const float* wqkv = (const float*)d_in[1];
    const float* wo = (const float*)d_in[2];
    const void* mask = d_in[3];
    float* out = (float*)d_out;

    char* ws = (char*)d_ws;
    int* flag = (int*)ws;                       // 16 B
    u16* xb = (u16*)(ws + 16);                  // 8388608 elems (reused as ctx later)
    u16* wqkvb = xb + 8388608;                  // 3145728
    u16* wob = wqkvb + 3145728;                 // 1048576
    u16* qw = wob + 1048576;                    // 8388608
    u16* kw = qw + 8388608;                     // 8388608
    u16* vw = kw + 8388608;                     // 8388608
    u16* ctx = xb;                              // reuse after GEMM1

    cvt_bf16_kernel<<<8192, 256, 0, stream>>>(x, xb, 8388608);
    cvt_bf16_kernel<<<3072, 256, 0, stream>>>(wqkv, wqkvb, 3145728);
    cvt_bf16_kernel<<<1024, 256, 0, stream>>>(wo, wob, 1048576);
    detect_mask_kernel<<<1, 256, 0, stream>>>((const unsigned char*)mask, flag);

    gemm_bt_kernel<0><<<dim3(24, 64), 256, 0, stream>>>(xb, wqkvb, 8192, 3072, 1024,
                                                        qw, kw, vw, nullptr);
    attn_kernel<<<dim3(16, 64), 256, 0, stream>>>(qw, kw, vw, mask, flag, ctx);
    gemm_bt_kernel<1><<<dim3(8, 64), 256, 0, stream>>>(ctx, wob, 8192, 1024, 1024,
                                                       nullptr, nullptr, nullptr, out);
}